// Round 12
// baseline (1639.883 us; speedup 1.0000x reference)
//
#include <hip/hip_runtime.h>
#include <math.h>

// ---- problem constants ----
#define V_   32000
#define D_   1024
#define H_   16
#define HD_  64
#define L_   6
#define F_   4096
#define S_   1024
#define B_   2
#define MTOK (B_*S_)      // 2048
#define EPSLN 1e-5f

typedef unsigned short ushort_t;
typedef __attribute__((ext_vector_type(8))) short  s16x8;
typedef __attribute__((ext_vector_type(4))) float  f32x4;
typedef __attribute__((ext_vector_type(4))) unsigned short u16x4;

__device__ __forceinline__ float bf2f(unsigned short u) {
    unsigned int x = ((unsigned int)u) << 16;
    return __builtin_bit_cast(float, x);
}
__device__ __forceinline__ unsigned short f2bf(float f) {
    unsigned int x = __builtin_bit_cast(unsigned int, f);
    unsigned int r = (x + 0x7FFFu + ((x >> 16) & 1u)) >> 16;   // RNE
    return (unsigned short)r;
}
__device__ __forceinline__ float gelu_f(float x) {
    float y = 0.7978845608f * (x + 0.044715f * x * x * x);
    float t = 1.0f - 2.0f / (__expf(2.0f * y) + 1.0f);
    return 0.5f * x * (1.0f + t);
}

__device__ __forceinline__ float blk_sum(float v, float* sb) {
    #pragma unroll
    for (int o = 32; o; o >>= 1) v += __shfl_xor(v, o, 64);
    int w = threadIdx.x >> 6;
    __syncthreads();
    if ((threadIdx.x & 63) == 0) sb[w] = v;
    __syncthreads();
    return sb[0] + sb[1] + sb[2] + sb[3];
}

// =====================================================================
// gemm256: 2-phase-per-K-tile pipelined 256x256xBK64 bf16 MFMA GEMM.
// Measured-best for the N=32000 logits shape (177us, 740 TF).
// =====================================================================
template<bool GELU, bool OUTBF>
__global__ __launch_bounds__(512, 2)
void gemm256(const ushort_t* __restrict__ A, int lda,
             const ushort_t* __restrict__ BT, int ldb,
             void* __restrict__ Cv, int ldc,
             const float* __restrict__ bias,
             int M, int N, int K)
{
    int nmt = M >> 8;
    int nwg = gridDim.x * gridDim.y;
    int id  = blockIdx.x + gridDim.x * blockIdx.y;
    int swz = ((nwg & 7) == 0) ? ((id & 7) * (nwg >> 3) + (id >> 3)) : id;
    int m0 = (swz % nmt) << 8;
    int n0 = (swz / nmt) << 8;

    __shared__ __align__(16) ushort_t lA[2][256 * 64];
    __shared__ __align__(16) ushort_t lB[2][256 * 64];

    int tid  = threadIdx.x;
    int lane = tid & 63, wave = tid >> 6;
    int lr = lane & 15, lg = lane >> 4;
    int wm = wave >> 2, wn = wave & 3;

    f32x4 acc[8][4] = {};
    int nkt = K >> 6;

    auto stageu = [&](int buf, int kt, int sel) {
        int k0 = kt << 6;
        const ushort_t* src = (sel < 2) ? A : BT;
        int ld    = (sel < 2) ? lda : ldb;
        int rbase = ((sel < 2) ? m0 : n0) + ((sel & 1) << 7);
        ushort_t* dst = ((sel < 2) ? &lA[buf][0] : &lB[buf][0]) + ((sel & 1) << 13);
        #pragma unroll
        for (int r = 0; r < 2; ++r) {
            int e8  = r * 512 + tid;
            int row = e8 >> 3, slot = e8 & 7;
            int ls  = slot ^ (row & 7);
            const ushort_t* g = src + (size_t)(rbase + row) * ld + k0 + ls * 8;
            __builtin_amdgcn_global_load_lds(
                (const __attribute__((address_space(1))) void*)g,
                (__attribute__((address_space(3))) void*)(dst + e8 * 8), 16, 0, 0);
        }
    };
    auto rdA = [&](int buf, int row, int ks) -> s16x8 {
        int sl = (lg + ks * 4) ^ (row & 7);
        return *(const s16x8*)&lA[buf][row * 64 + sl * 8];
    };
    auto rdB = [&](int buf, int row, int ks) -> s16x8 {
        int sl = (lg + ks * 4) ^ (row & 7);
        return *(const s16x8*)&lB[buf][row * 64 + sl * 8];
    };

    stageu(0, 0, 0); stageu(0, 0, 1); stageu(0, 0, 2); stageu(0, 0, 3);
    if (nkt > 1) {
        stageu(1, 1, 2); stageu(1, 1, 3);
        asm volatile("s_waitcnt vmcnt(4)" ::: "memory");
    } else {
        asm volatile("s_waitcnt vmcnt(0)" ::: "memory");
    }
    __builtin_amdgcn_sched_barrier(0);
    __builtin_amdgcn_s_barrier();

    for (int u = 0; u < nkt; ++u) {
        int cur = u & 1, nxt = cur ^ 1;
        s16x8 af0[4][2], af1[4][2], bf0[2][2], bf1[2][2];

        // ======== Phase A: af0 + bf0 + bf1 reads; stage A(u+1) ========
        #pragma unroll
        for (int mf = 0; mf < 4; ++mf)
            #pragma unroll
            for (int ks = 0; ks < 2; ++ks)
                af0[mf][ks] = rdA(cur, wm * 128 + mf * 16 + lr, ks);
        #pragma unroll
        for (int nf = 0; nf < 2; ++nf)
            #pragma unroll
            for (int ks = 0; ks < 2; ++ks) {
                bf0[nf][ks] = rdB(cur, wn * 64 + nf * 16 + lr, ks);
                bf1[nf][ks] = rdB(cur, wn * 64 + 32 + nf * 16 + lr, ks);
            }
        if (u + 1 < nkt) { stageu(nxt, u + 1, 0); stageu(nxt, u + 1, 1); }
        __builtin_amdgcn_s_barrier();
        asm volatile("s_waitcnt lgkmcnt(0)" ::: "memory");
        __builtin_amdgcn_sched_barrier(0);
        __builtin_amdgcn_s_setprio(1);
        #pragma unroll
        for (int mf = 0; mf < 4; ++mf)
            #pragma unroll
            for (int ks = 0; ks < 2; ++ks) {
                #pragma unroll
                for (int nf = 0; nf < 2; ++nf) {
                    acc[mf][nf]     = __builtin_amdgcn_mfma_f32_16x16x32_bf16(
                        af0[mf][ks], bf0[nf][ks], acc[mf][nf], 0, 0, 0);
                    acc[mf][2 + nf] = __builtin_amdgcn_mfma_f32_16x16x32_bf16(
                        af0[mf][ks], bf1[nf][ks], acc[mf][2 + nf], 0, 0, 0);
                }
            }
        __builtin_amdgcn_s_setprio(0);
        __builtin_amdgcn_s_barrier();

        // ======== Phase B: af1 reads; stage B(u+2) into cur ========
        #pragma unroll
        for (int mf = 0; mf < 4; ++mf)
            #pragma unroll
            for (int ks = 0; ks < 2; ++ks)
                af1[mf][ks] = rdA(cur, wm * 128 + 64 + mf * 16 + lr, ks);
        if (u + 2 < nkt) { stageu(cur, u + 2, 2); stageu(cur, u + 2, 3); }
        __builtin_amdgcn_s_barrier();
        asm volatile("s_waitcnt lgkmcnt(0)" ::: "memory");
        __builtin_amdgcn_sched_barrier(0);
        __builtin_amdgcn_s_setprio(1);
        #pragma unroll
        for (int mf = 0; mf < 4; ++mf)
            #pragma unroll
            for (int ks = 0; ks < 2; ++ks) {
                #pragma unroll
                for (int nf = 0; nf < 2; ++nf) {
                    acc[4 + mf][nf]     = __builtin_amdgcn_mfma_f32_16x16x32_bf16(
                        af1[mf][ks], bf0[nf][ks], acc[4 + mf][nf], 0, 0, 0);
                    acc[4 + mf][2 + nf] = __builtin_amdgcn_mfma_f32_16x16x32_bf16(
                        af1[mf][ks], bf1[nf][ks], acc[4 + mf][2 + nf], 0, 0, 0);
                }
            }
        __builtin_amdgcn_s_setprio(0);
        if (u + 2 < nkt) asm volatile("s_waitcnt vmcnt(4)" ::: "memory");
        else             asm volatile("s_waitcnt vmcnt(0)" ::: "memory");
        __builtin_amdgcn_sched_barrier(0);
        __builtin_amdgcn_s_barrier();
    }

    float*    Cf = (float*)Cv;
    ushort_t* Cb = (ushort_t*)Cv;
    #pragma unroll
    for (int mf = 0; mf < 8; ++mf) {
        int gm0 = m0 + wm * 128 + mf * 16 + lg * 4;
        #pragma unroll
        for (int nf = 0; nf < 4; ++nf) {
            int gn = n0 + wn * 64 + nf * 16 + lr;
            float bv = bias ? bias[gn] : 0.f;
            #pragma unroll
            for (int j = 0; j < 4; ++j) {
                float v = acc[mf][nf][j] + bv;
                if (GELU) v = gelu_f(v);
                size_t ci = (size_t)(gm0 + j) * ldc + gn;
                if (OUTBF) Cb[ci] = f2bf(v);
                else       Cf[ci] = v;
            }
        }
    }
}

// =====================================================================
// gemm_bt: 128xBNxBK64, 2-phase dbuf + 8-slot XOR swizzle. BN in {64,128}.
// BK=64 halves barrier count vs BK=32. XCD-chunked block swizzle.
// VOUT: for QKV, also scatter V columns (gn>=2048) into vt[BH][HD][S].
// NOTE r11 lesson: QKV (N=3072) must use BN=128 — BN=64 doubled A-staging
// and halved MFMA-per-barrier, costing +19us/layer.
// =====================================================================
template<int BN, bool GELU, bool RES, bool OUTBF, bool VOUT>
__global__ __launch_bounds__(256)
void gemm_bt(const ushort_t* __restrict__ A, int lda,
             const ushort_t* __restrict__ BT, int ldb,
             void* __restrict__ Cv, int ldc,
             const float* __restrict__ bias,
             const float* __restrict__ res,
             int M, int N, int K, ushort_t* __restrict__ vtp)
{
    const int BK = 64;
    const int NF = BN / 32;          // n-frags per wave
    int nwg = gridDim.x * gridDim.y;
    int id  = blockIdx.x + gridDim.x * blockIdx.y;
    int swz = ((nwg & 7) == 0) ? ((id & 7) * (nwg >> 3) + (id >> 3)) : id;
    int m0 = (swz % gridDim.x) * 128;
    int n0 = (swz / gridDim.x) * BN;

    __shared__ __align__(16) ushort_t lA[2][128 * BK];
    __shared__ __align__(16) ushort_t lB[2][BN * BK];

    int tid  = threadIdx.x;
    int lane = tid & 63;
    int wave = tid >> 6;
    int lr = lane & 15, lg = lane >> 4;
    int wr = wave >> 1, wc = wave & 1;

    f32x4 acc[4][NF] = {};
    int nkt = K / BK;

    auto stage = [&](int buf, int kt) {
        int k0 = kt * BK;
        #pragma unroll
        for (int i = 0; i < 4; ++i) {
            int e8  = i * 256 + tid;           // 16B units, 0..1023
            int row = e8 >> 3, slot = e8 & 7;
            int ls  = slot ^ (row & 7);
            const ushort_t* g = A + (size_t)(m0 + row) * lda + k0 + ls * 8;
            __builtin_amdgcn_global_load_lds(
                (const __attribute__((address_space(1))) void*)g,
                (__attribute__((address_space(3))) void*)&lA[buf][e8 * 8], 16, 0, 0);
        }
        #pragma unroll
        for (int i = 0; i < BN / 32; ++i) {
            int e8  = i * 256 + tid;
            int row = e8 >> 3, slot = e8 & 7;
            int ls  = slot ^ (row & 7);
            const ushort_t* g = BT + (size_t)(n0 + row) * ldb + k0 + ls * 8;
            __builtin_amdgcn_global_load_lds(
                (const __attribute__((address_space(1))) void*)g,
                (__attribute__((address_space(3))) void*)&lB[buf][e8 * 8], 16, 0, 0);
        }
    };

    stage(0, 0);
    __syncthreads();

    int cur = 0;
    for (int kt = 0; kt < nkt; ++kt) {
        if (kt + 1 < nkt) stage(cur ^ 1, kt + 1);
        __builtin_amdgcn_sched_barrier(0);
        s16x8 af[4][2], bfr[NF][2];
        #pragma unroll
        for (int m = 0; m < 4; ++m) {
            int row = wr * 64 + m * 16 + lr;
            #pragma unroll
            for (int ks = 0; ks < 2; ++ks) {
                int sl = (lg + ks * 4) ^ (row & 7);
                af[m][ks] = *(const s16x8*)&lA[cur][row * BK + sl * 8];
            }
        }
        #pragma unroll
        for (int n = 0; n < NF; ++n) {
            int row = wc * (BN / 2) + n * 16 + lr;
            #pragma unroll
            for (int ks = 0; ks < 2; ++ks) {
                int sl = (lg + ks * 4) ^ (row & 7);
                bfr[n][ks] = *(const s16x8*)&lB[cur][row * BK + sl * 8];
            }
        }
        __builtin_amdgcn_s_setprio(1);
        #pragma unroll
        for (int m = 0; m < 4; ++m)
            #pragma unroll
            for (int n = 0; n < NF; ++n)
                #pragma unroll
                for (int ks = 0; ks < 2; ++ks)
                    acc[m][n] = __builtin_amdgcn_mfma_f32_16x16x32_bf16(
                        af[m][ks], bfr[n][ks], acc[m][n], 0, 0, 0);
        __builtin_amdgcn_s_setprio(0);
        __syncthreads();
        cur ^= 1;
    }

    float*    Cf = (float*)Cv;
    ushort_t* Cb = (ushort_t*)Cv;
    #pragma unroll
    for (int m = 0; m < 4; ++m) {
        int gm0 = m0 + wr * 64 + m * 16 + lg * 4;
        #pragma unroll
        for (int n = 0; n < NF; ++n) {
            int gn = n0 + wc * (BN / 2) + n * 16 + lr;
            #pragma unroll
            for (int j = 0; j < 4; ++j) {
                float v = acc[m][n][j];
                if (bias) v += bias[gn];
                size_t ci = (size_t)(gm0 + j) * ldc + gn;
                if (RES)  v += res[ci];
                if (GELU) v = gelu_f(v);
                if (OUTBF) Cb[ci] = f2bf(v);
                else       Cf[ci] = v;
                if (VOUT && gn >= 2048) {
                    int hv = gn - 2048;
                    int mm = gm0 + j;
                    vtp[((size_t)(((mm >> 10) << 4) + (hv >> 6)) * 64
                         + (hv & 63)) * 1024 + (mm & 1023)] = f2bf(v);
                }
            }
        }
    }
}

// =====================================================================
// Flash attention, LOAD-BALANCED: grid (8, BH). Block x processes
// q-tiles {x, 15-x}: 17 KV-iters for EVERY block. K/V double-buffered
// with top-of-iter prefetch; setprio around MFMA clusters.
// =====================================================================
__global__ __launch_bounds__(256)
void flash_attn(const ushort_t* __restrict__ qkv,
                const ushort_t* __restrict__ vt,
                ushort_t* __restrict__ ctx)
{
    const int QB = 64, KB = 64;
    int z  = blockIdx.y;            // b*H + h
    int b  = z >> 4, hh = z & 15;

    __shared__ __align__(16) ushort_t Qs[QB * 64];
    __shared__ __align__(16) ushort_t Ks[2][KB * 64];
    __shared__ __align__(16) ushort_t Vs[2][64 * KB];
    __shared__ float    Ss[QB][68];
    __shared__ __align__(16) ushort_t Ps[QB][72];
    __shared__ float mrow[QB], lrow[QB], arow[QB];

    int tid  = threadIdx.x;
    int lane = tid & 63, wave = tid >> 6;
    int lr = lane & 15, lg = lane >> 4;
    int r = tid >> 2, p = tid & 3;

    auto stageKV = [&](int buf, int kv0) {
        const ushort_t* kbase = qkv + (size_t)(b * S_ + kv0) * 3072 + 1024 + hh * HD_;
        const ushort_t* vbase = vt + (size_t)z * HD_ * S_ + kv0;
        #pragma unroll
        for (int rnd = 0; rnd < 2; ++rnd) {
            int e8 = rnd * 256 + tid;
            int row = e8 >> 3, slot = e8 & 7;
            int ls = slot ^ (row & 7);
            const ushort_t* gk = kbase + (size_t)row * 3072 + ls * 8;
            __builtin_amdgcn_global_load_lds(
                (const __attribute__((address_space(1))) void*)gk,
                (__attribute__((address_space(3))) void*)&Ks[buf][e8 * 8], 16, 0, 0);
            const ushort_t* gv = vbase + (size_t)row * S_ + ls * 8;
            __builtin_amdgcn_global_load_lds(
                (const __attribute__((address_space(1))) void*)gv,
                (__attribute__((address_space(3))) void*)&Vs[buf][e8 * 8], 16, 0, 0);
        }
    };

    #pragma unroll
    for (int half = 0; half < 2; ++half) {
        int qt = half ? (15 - (int)blockIdx.x) : (int)blockIdx.x;
        int q0 = qt * QB;

        if (tid < QB) { mrow[tid] = -1e30f; lrow[tid] = 0.f; }
        const ushort_t* qbase = qkv + (size_t)(b * S_ + q0) * 3072 + hh * HD_;
        #pragma unroll
        for (int rnd = 0; rnd < 2; ++rnd) {
            int e8   = rnd * 256 + tid;
            int row  = e8 >> 3;
            int slot = e8 & 7;
            int ls   = slot ^ (row & 7);
            const ushort_t* g = qbase + (size_t)row * 3072 + ls * 8;
            __builtin_amdgcn_global_load_lds(
                (const __attribute__((address_space(1))) void*)g,
                (__attribute__((address_space(3))) void*)&Qs[e8 * 8], 16, 0, 0);
        }
        stageKV(0, 0);
        __syncthreads();

        s16x8 qa[4][2];
        #pragma unroll
        for (int mf = 0; mf < 4; ++mf)
            #pragma unroll
            for (int ks = 0; ks < 2; ++ks) {
                int row = mf * 16 + lr;
                int sl  = (lg + ks * 4) ^ (row & 7);
                qa[mf][ks] = *(const s16x8*)&Qs[row * 64 + sl * 8];
            }

        f32x4 acc[4] = {};
        int kv_end = q0 + QB;
        int cur = 0;
        for (int kv0 = 0; kv0 < kv_end; kv0 += KB) {
            if (kv0 + KB < kv_end) stageKV(cur ^ 1, kv0 + KB);

            s16x8 kb[2];
            #pragma unroll
            for (int ks = 0; ks < 2; ++ks) {
                int row = wave * 16 + lr;
                int sl  = (lg + ks * 4) ^ (row & 7);
                kb[ks] = *(const s16x8*)&Ks[cur][row * 64 + sl * 8];
            }
            f32x4 sa[4] = {};
            __builtin_amdgcn_s_setprio(1);
            #pragma unroll
            for (int mf = 0; mf < 4; ++mf)
                #pragma unroll
                for (int ks = 0; ks < 2; ++ks)
                    sa[mf] = __builtin_amdgcn_mfma_f32_16x16x32_bf16(
                        qa[mf][ks], kb[ks], sa[mf], 0, 0, 0);
            __builtin_amdgcn_s_setprio(0);

            int ki = kv0 + wave * 16 + lr;
            #pragma unroll
            for (int mf = 0; mf < 4; ++mf)
                #pragma unroll
                for (int j = 0; j < 4; ++j) {
                    int qi = q0 + mf * 16 + lg * 4 + j;
                    float s = (ki <= qi) ? sa[mf][j] * 0.125f : -1e30f;
                    Ss[mf * 16 + lg * 4 + j][wave * 16 + lr] = s;
                }
            __syncthreads();

            float mo = mrow[r];
            float sv[16];
            float pm = -1e30f;
            #pragma unroll
            for (int i = 0; i < 16; ++i) {
                sv[i] = Ss[r][p * 16 + i];
                pm = fmaxf(pm, sv[i]);
            }
            pm = fmaxf(pm, __shfl_xor(pm, 1, 64));
            pm = fmaxf(pm, __shfl_xor(pm, 2, 64));
            float M = fmaxf(mo, pm);
            float sum = 0.f;
            s16x8 pk0, pk1;
            #pragma unroll
            for (int i = 0; i < 8; ++i) {
                float e0 = __expf(sv[i] - M);
                float e1 = __expf(sv[i + 8] - M);
                sum += e0 + e1;
                pk0[i] = (short)f2bf(e0);
                pk1[i] = (short)f2bf(e1);
            }
            *(s16x8*)&Ps[r][p * 16]     = pk0;
            *(s16x8*)&Ps[r][p * 16 + 8] = pk1;
            sum += __shfl_xor(sum, 1, 64);
            sum += __shfl_xor(sum, 2, 64);
            if (p == 0) {
                float al = __expf(mo - M);
                arow[r] = al;
                mrow[r] = M;
                lrow[r] = lrow[r] * al + sum;
            }
            __syncthreads();

            #pragma unroll
            for (int mf = 0; mf < 4; ++mf) {
                #pragma unroll
                for (int j = 0; j < 4; ++j)
                    acc[mf][j] *= arow[mf * 16 + lg * 4 + j];
            }
            s16x8 vb[2];
            #pragma unroll
            for (int ks = 0; ks < 2; ++ks) {
                int row = wave * 16 + lr;
                int sl  = (lg + ks * 4) ^ (row & 7);
                vb[ks] = *(const s16x8*)&Vs[cur][row * 64 + sl * 8];
            }
            __builtin_amdgcn_s_setprio(1);
            #pragma unroll
            for (int mf = 0; mf < 4; ++mf)
                #pragma unroll
                for (int ks = 0; ks < 2; ++ks) {
                    s16x8 pa = *(const s16x8*)((const char*)&Ps[0][0]
                                + (mf * 16 + lr) * 144 + lg * 16 + ks * 64);
                    acc[mf] = __builtin_amdgcn_mfma_f32_16x16x32_bf16(
                        pa, vb[ks], acc[mf], 0, 0, 0);
                }
            __builtin_amdgcn_s_setprio(0);
            __syncthreads();
            cur ^= 1;
        }

        #pragma unroll
        for (int mf = 0; mf < 4; ++mf)
            #pragma unroll
            for (int j = 0; j < 4; ++j) {
                int rr = mf * 16 + lg * 4 + j;
                float o = acc[mf][j] / lrow[rr];
                ctx[(size_t)(b * S_ + q0 + rr) * D_ + hh * HD_ + wave * 16 + lr] = f2bf(o);
            }
        __syncthreads();   // protect Qs/Ks/Vs/state before next half
    }
}

// =====================================================================
// prep_all: weight transpose+convert for nl layers (+ optional Wout) +
// qkv bias concat, in ONE launch. Per layer 3075 blocks.
// =====================================================================
#define DD_ (D_*D_)
#define DF_ (D_*F_)
#define WL_ (3*DD_ + DD_ + DF_ + DF_)
__global__ __launch_bounds__(256)
void prep_all(const float* __restrict__ Wq, const float* __restrict__ Wk,
              const float* __restrict__ Wv, const float* __restrict__ Wo,
              const float* __restrict__ W1, const float* __restrict__ W2,
              const float* __restrict__ bq, const float* __restrict__ bk,
              const float* __restrict__ bv,
              ushort_t* __restrict__ wAll, float* __restrict__ qkvbAll,
              int nl,
              const float* __restrict__ Wout, ushort_t* __restrict__ wouT)
{
    int bid = blockIdx.x;
    int nwl = nl * 3075;
    __shared__ float t[64][65];
    int tid = threadIdx.x;
    int tx = tid & 63, ty = tid >> 6;
    const float* src; ushort_t* dst; int R, C, c0, r0;

    if (bid < nwl) {
        int layer = bid / 3075, sub = bid % 3075;
        if (sub >= 3072) {
            int j = sub - 3072;
            const float* bsrc = ((j == 0) ? bq : (j == 1) ? bk : bv) + (size_t)layer * D_;
            int c = tid * 4;
            *(f32x4*)&qkvbAll[(size_t)layer * 3072 + j * 1024 + c] = *(const f32x4*)&bsrc[c];
            return;
        }
        ushort_t* wl = wAll + (size_t)layer * WL_;
        if (sub < 1024) {
            int mat = sub >> 8, tnum = sub & 255;
            src = ((mat == 0) ? Wq : (mat == 1) ? Wk : (mat == 2) ? Wv : Wo)
                  + (size_t)layer * DD_;
            dst = (mat < 3) ? (wl + (size_t)mat * DD_) : (wl + 3 * (size_t)DD_);
            R = D_; C = D_;
            c0 = (tnum & 15) * 64; r0 = (tnum >> 4) * 64;
        } else if (sub < 2048) {
            int tnum = sub - 1024;
            src = W1 + (size_t)layer * DF_; dst = wl + 4 * (size_t)DD_;
            R = D_; C = F_;
            c0 = (tnum & 63) * 64; r0 = (tnum >> 6) * 64;
        } else {
            int tnum = sub - 2048;
            src = W2 + (size_t)layer * DF_; dst = wl + 4 * (size_t)DD_ + (size_t)DF_;
            R = F_; C = D_;
            c0 = (tnum & 15) * 64; r0 = (tnum >> 4) * 64;
        }
    } else {
        int tnum = bid - nwl;                 // Wout tiles: 500 x 16
        src = Wout; dst = wouT; R = D_; C = V_;
        c0 = (tnum % 500) * 64; r0 = (tnum / 500) * 64;
    }
    #pragma unroll
    for (int i = 0; i < 16; ++i)
        t[ty + i * 4][tx] = src[(size_t)(r0 + ty + i * 4) * C + c0 + tx];
    __syncthreads();
    int u = tid & 31, v = tid >> 5;
    #pragma unroll
    for (int i = 0; i < 8; ++i) {
        int cc = v + i * 8;
        unsigned int val = (unsigned int)f2bf(t[u * 2][cc])
                         | ((unsigned int)f2bf(t[u * 2 + 1][cc]) << 16);
        *(unsigned int*)&dst[(size_t)(c0 + cc) * R + r0 + u * 2] = val;
    }
}

// ---- f32 [R,C] -> bf16 [C,R] transpose-convert, 64x64 tiles (fallback) ----
__global__ __launch_bounds__(256)
void tconv(const float* __restrict__ in, ushort_t* __restrict__ out, int R, int C)
{
    __shared__ float t[64][65];
    int c0 = blockIdx.x * 64, r0 = blockIdx.y * 64;
    int tid = threadIdx.x;
    int tx = tid & 63, ty = tid >> 6;
    #pragma unroll
    for (int i = 0; i < 16; ++i)
        t[ty + i * 4][tx] = in[(size_t)(r0 + ty + i * 4) * C + c0 + tx];
    __syncthreads();
    int u = tid & 31, v = tid >> 5;
    #pragma unroll
    for (int i = 0; i < 8; ++i) {
        int cc = v + i * 8;
        unsigned int val = (unsigned int)f2bf(t[u * 2][cc])
                         | ((unsigned int)f2bf(t[u * 2 + 1][cc]) << 16);
        *(unsigned int*)&out[(size_t)(c0 + cc) * R + r0 + u * 2] = val;
    }
}

// ---- embedding * sqrt(D) + sinusoidal PE -> x (f32) ----
__global__ __launch_bounds__(256)
void embed_pe(const int* __restrict__ ids, const float* __restrict__ emb,
              float* __restrict__ x)
{
    int row = blockIdx.x;
    int s   = row & (S_ - 1);
    int id  = ids[row];
    int d   = threadIdx.x * 4;
    f32x4 ev = *(const f32x4*)&emb[(size_t)id * D_ + d];
    f32x4 o;
    #pragma unroll
    for (int j = 0; j < 4; ++j) {
        int dd = d + j;
        int i  = dd >> 1;
        float div = expf(-(float)(2 * i) * (9.210340371976184f / 1024.0f));
        float arg = (float)s * div;
        float pe  = (dd & 1) ? cosf(arg) : sinf(arg);
        o[j] = ev[j] * 32.0f + pe;
    }
    *(f32x4*)&x[(size_t)row * D_ + d] = o;
}

// ---- LayerNorm row kernel: f32 in -> bf16 out ----
__global__ __launch_bounds__(256)
void ln_kernel(const float* __restrict__ x, const float* __restrict__ g,
               const float* __restrict__ b, ushort_t* __restrict__ out)
{
    __shared__ float sb[4];
    int row = blockIdx.x;
    const float* xr = x + (size_t)row * D_;
    int c = threadIdx.x * 4;
    f32x4 v = *(const f32x4*)&xr[c];
    float s = v[0] + v[1] + v[2] + v[3];
    s = blk_sum(s, sb);
    float mean = s * (1.0f / D_);
    f32x4 dv = v - mean;
    float sq = dv[0]*dv[0] + dv[1]*dv[1] + dv[2]*dv[2] + dv[3]*dv[3];
    sq = blk_sum(sq, sb);
    float rstd = rsqrtf(sq * (1.0f / D_) + EPSLN);
    u16x4 o;
    #pragma unroll
    for (int j = 0; j < 4; ++j)
        o[j] = f2bf(dv[j] * rstd * g[c + j] + b[c + j]);
    *(u16x4*)&out[(size_t)row * D_ + c] = o;
}

__global__ void ws_marker(float* o) { o[threadIdx.x] = -777777.0f; }

// =====================================================================
extern "C" void kernel_launch(void* const* d_in, const int* in_sizes, int n_in,
                              void* d_out, int out_size, void* d_ws, size_t ws_size,
                              hipStream_t stream)
{
    (void)in_sizes; (void)n_in; (void)out_size;
    const int*   ids  = (const int*)d_in[0];
    const float* emb  = (const float*)d_in[1];
    const float* Wq   = (const float*)d_in[2];
    const float* bq   = (const float*)d_in[3];
    const float* Wk   = (const float*)d_in[4];
    const float* bk   = (const float*)d_in[5];
    const float* Wv   = (const float*)d_in[6];
    const float* bv   = (const float*)d_in[7];
    const float* Wo   = (const float*)d_in[8];
    const float* bo   = (const float*)d_in[9];
    const float* ln1g = (const float*)d_in[10];
    const float* ln1b = (const float*)d_in[11];
    const float* ln2g = (const float*)d_in[12];
    const float* ln2b = (const float*)d_in[13];
    const float* W1   = (const float*)d_in[14];
    const float* b1   = (const float*)d_in[15];
    const float* W2   = (const float*)d_in[16];
    const float* b2   = (const float*)d_in[17];
    const float* fng  = (const float*)d_in[18];
    const float* fnb  = (const float*)d_in[19];
    const float* Wout = (const float*)d_in[20];
    const float* bout = (const float*)d_in[21];
    float* out = (float*)d_out;

    // ---- workspace layout (shared part) ----
    char* base = (char*)d_ws;
    size_t off = 0;
    float*    x    = (float*)(base + off);    off += (size_t)MTOK * D_ * 4;
    ushort_t* h    = (ushort_t*)(base + off); off += (size_t)MTOK * D_ * 2;
    ushort_t* qkv  = (ushort_t*)(base + off); off += (size_t)MTOK * 3 * D_ * 2;
    ushort_t* vt   = (ushort_t*)(base + off); off += (size_t)B_ * H_ * HD_ * S_ * 2;
    ushort_t* ctx  = (ushort_t*)(base + off); off += (size_t)MTOK * D_ * 2;
    ushort_t* ff   = (ushort_t*)(base + off); off += (size_t)MTOK * F_ * 2;
    float*    qkvbA= (float*)(base + off);    off += (size_t)L_ * 3072 * 4;
    ushort_t* wouT = (ushort_t*)(base + off); off += (size_t)V_ * D_ * 2;
    ushort_t* wAll = (ushort_t*)(base + off);
    size_t off_small = off + (size_t)WL_ * 2;            // 1 layer of weights
    size_t off_big   = off + (size_t)L_ * WL_ * 2;       // all 6 layers
    bool big = (ws_size >= off_big);
    if (!big && ws_size < off_small) { ws_marker<<<1, 64, 0, stream>>>(out); return; }

    embed_pe<<<MTOK, 256, 0, stream>>>(ids, emb, x);

    if (big) {
        // one launch: all 6 layers' weights + Wout (8000 tiles)
        prep_all<<<L_ * 3075 + 8000, 256, 0, stream>>>(
            Wq, Wk, Wv, Wo, W1, W2, bq, bk, bv, wAll, qkvbA, L_, Wout, wouT);
    }

    for (int i = 0; i < L_; ++i) {
        ushort_t* wl    = wAll + (big ? (size_t)i * WL_ : 0);
        float*    qkvb  = qkvbA + (big ? (size_t)i * 3072 : 0);
        if (!big) {
            prep_all<<<3075, 256, 0, stream>>>(
                Wq + (size_t)i * DD_, Wk + (size_t)i * DD_,
                Wv + (size_t)i * DD_, Wo + (size_t)i * DD_,
                W1 + (size_t)i * DF_, W2 + (size_t)i * DF_,
                bq + i * D_, bk + i * D_, bv + i * D_,
                wl, qkvb, 1, nullptr, nullptr);
        }
        ushort_t* wqkvT = wl;
        ushort_t* woT   = wl + 3 * (size_t)DD_;
        ushort_t* w1T   = wl + 4 * (size_t)DD_;
        ushort_t* w2T   = wl + 4 * (size_t)DD_ + (size_t)DF_;

        ln_kernel<<<MTOK, 256, 0, stream>>>(x, ln1g + i * D_, ln1b + i * D_, h);

        // qkv = h @ [Wq|Wk|Wv] + bias; V cols also scattered into vt
        // BN=128 (r10 measured-best; r11's BN=64 cost +19us/layer)
        gemm_bt<128,false,false,true,true><<<dim3(16, 24), 256, 0, stream>>>(
            h, D_, wqkvT, D_, qkv, 3 * D_, qkvb, nullptr, MTOK, 3 * D_, D_, vt);

        flash_attn<<<dim3(8, B_ * H_), 256, 0, stream>>>(qkv, vt, ctx);

        // x = x + ctx @ Wo + bo
        gemm_bt<64,false,true,false,false><<<dim3(16, 16), 256, 0, stream>>>(
            ctx, D_, woT, D_, x, D_, bo + i * D_, x, MTOK, D_, D_, nullptr);

        ln_kernel<<<MTOK, 256, 0, stream>>>(x, ln2g + i * D_, ln2b + i * D_, h);

        // ff = gelu(h @ W1 + b1)
        gemm_bt<128,true,false,true,false><<<dim3(16, 32), 256, 0, stream>>>(
            h, D_, w1T, D_, ff, F_, b1 + i * F_, nullptr, MTOK, F_, D_, nullptr);

        // x = x + ff @ W2 + b2
        gemm_bt<64,false,true,false,false><<<dim3(16, 16), 256, 0, stream>>>(
            ff, F_, w2T, F_, x, D_, b2 + i * D_, x, MTOK, D_, F_, nullptr);
    }

    ln_kernel<<<MTOK, 256, 0, stream>>>(x, fng, fnb, h);
    if (!big) tconv<<<dim3(500, 16), 256, 0, stream>>>(Wout, wouT, D_, V_);
    // logits: 256^2 tiles (measured-best for N=32000)
    gemm256<false,false><<<dim3(8, 125), 512, 0, stream>>>(
        h, D_, wouT, D_, out, V_, bout, MTOK, V_, D_);
}

// Round 13
// 1433.895 us; speedup vs baseline: 1.1437x; 1.1437x over previous
//
#include <hip/hip_runtime.h>
#include <math.h>

// ---- problem constants ----
#define V_   32000
#define D_   1024
#define H_   16
#define HD_  64
#define L_   6
#define F_   4096
#define S_   1024
#define B_   2
#define MTOK (B_*S_)      // 2048
#define EPSLN 1e-5f

typedef unsigned short ushort_t;
typedef __attribute__((ext_vector_type(8))) short  s16x8;
typedef __attribute__((ext_vector_type(4))) float  f32x4;
typedef __attribute__((ext_vector_type(4))) unsigned short u16x4;

__device__ __forceinline__ float bf2f(unsigned short u) {
    unsigned int x = ((unsigned int)u) << 16;
    return __builtin_bit_cast(float, x);
}
__device__ __forceinline__ unsigned short f2bf(float f) {
    unsigned int x = __builtin_bit_cast(unsigned int, f);
    unsigned int r = (x + 0x7FFFu + ((x >> 16) & 1u)) >> 16;   // RNE
    return (unsigned short)r;
}
__device__ __forceinline__ float gelu_f(float x) {
    float y = 0.7978845608f * (x + 0.044715f * x * x * x);
    float t = 1.0f - 2.0f / (__expf(2.0f * y) + 1.0f);
    return 0.5f * x * (1.0f + t);
}

__device__ __forceinline__ float blk_sum(float v, float* sb) {
    #pragma unroll
    for (int o = 32; o; o >>= 1) v += __shfl_xor(v, o, 64);
    int w = threadIdx.x >> 6;
    __syncthreads();
    if ((threadIdx.x & 63) == 0) sb[w] = v;
    __syncthreads();
    return sb[0] + sb[1] + sb[2] + sb[3];
}

// =====================================================================
// gemm256: 2-phase-per-K-tile pipelined 256x256xBK64 bf16 MFMA GEMM.
// Measured-best for the N=32000 logits shape (177us, 740 TF).
// =====================================================================
template<bool GELU, bool OUTBF>
__global__ __launch_bounds__(512, 2)
void gemm256(const ushort_t* __restrict__ A, int lda,
             const ushort_t* __restrict__ BT, int ldb,
             void* __restrict__ Cv, int ldc,
             const float* __restrict__ bias,
             int M, int N, int K)
{
    int nmt = M >> 8;
    int nwg = gridDim.x * gridDim.y;
    int id  = blockIdx.x + gridDim.x * blockIdx.y;
    int swz = ((nwg & 7) == 0) ? ((id & 7) * (nwg >> 3) + (id >> 3)) : id;
    int m0 = (swz % nmt) << 8;
    int n0 = (swz / nmt) << 8;

    __shared__ __align__(16) ushort_t lA[2][256 * 64];
    __shared__ __align__(16) ushort_t lB[2][256 * 64];

    int tid  = threadIdx.x;
    int lane = tid & 63, wave = tid >> 6;
    int lr = lane & 15, lg = lane >> 4;
    int wm = wave >> 2, wn = wave & 3;

    f32x4 acc[8][4] = {};
    int nkt = K >> 6;

    auto stageu = [&](int buf, int kt, int sel) {
        int k0 = kt << 6;
        const ushort_t* src = (sel < 2) ? A : BT;
        int ld    = (sel < 2) ? lda : ldb;
        int rbase = ((sel < 2) ? m0 : n0) + ((sel & 1) << 7);
        ushort_t* dst = ((sel < 2) ? &lA[buf][0] : &lB[buf][0]) + ((sel & 1) << 13);
        #pragma unroll
        for (int r = 0; r < 2; ++r) {
            int e8  = r * 512 + tid;
            int row = e8 >> 3, slot = e8 & 7;
            int ls  = slot ^ (row & 7);
            const ushort_t* g = src + (size_t)(rbase + row) * ld + k0 + ls * 8;
            __builtin_amdgcn_global_load_lds(
                (const __attribute__((address_space(1))) void*)g,
                (__attribute__((address_space(3))) void*)(dst + e8 * 8), 16, 0, 0);
        }
    };
    auto rdA = [&](int buf, int row, int ks) -> s16x8 {
        int sl = (lg + ks * 4) ^ (row & 7);
        return *(const s16x8*)&lA[buf][row * 64 + sl * 8];
    };
    auto rdB = [&](int buf, int row, int ks) -> s16x8 {
        int sl = (lg + ks * 4) ^ (row & 7);
        return *(const s16x8*)&lB[buf][row * 64 + sl * 8];
    };

    stageu(0, 0, 0); stageu(0, 0, 1); stageu(0, 0, 2); stageu(0, 0, 3);
    if (nkt > 1) {
        stageu(1, 1, 2); stageu(1, 1, 3);
        asm volatile("s_waitcnt vmcnt(4)" ::: "memory");
    } else {
        asm volatile("s_waitcnt vmcnt(0)" ::: "memory");
    }
    __builtin_amdgcn_sched_barrier(0);
    __builtin_amdgcn_s_barrier();

    for (int u = 0; u < nkt; ++u) {
        int cur = u & 1, nxt = cur ^ 1;
        s16x8 af0[4][2], af1[4][2], bf0[2][2], bf1[2][2];

        // ======== Phase A: af0 + bf0 + bf1 reads; stage A(u+1) ========
        #pragma unroll
        for (int mf = 0; mf < 4; ++mf)
            #pragma unroll
            for (int ks = 0; ks < 2; ++ks)
                af0[mf][ks] = rdA(cur, wm * 128 + mf * 16 + lr, ks);
        #pragma unroll
        for (int nf = 0; nf < 2; ++nf)
            #pragma unroll
            for (int ks = 0; ks < 2; ++ks) {
                bf0[nf][ks] = rdB(cur, wn * 64 + nf * 16 + lr, ks);
                bf1[nf][ks] = rdB(cur, wn * 64 + 32 + nf * 16 + lr, ks);
            }
        if (u + 1 < nkt) { stageu(nxt, u + 1, 0); stageu(nxt, u + 1, 1); }
        __builtin_amdgcn_s_barrier();
        asm volatile("s_waitcnt lgkmcnt(0)" ::: "memory");
        __builtin_amdgcn_sched_barrier(0);
        __builtin_amdgcn_s_setprio(1);
        #pragma unroll
        for (int mf = 0; mf < 4; ++mf)
            #pragma unroll
            for (int ks = 0; ks < 2; ++ks) {
                #pragma unroll
                for (int nf = 0; nf < 2; ++nf) {
                    acc[mf][nf]     = __builtin_amdgcn_mfma_f32_16x16x32_bf16(
                        af0[mf][ks], bf0[nf][ks], acc[mf][nf], 0, 0, 0);
                    acc[mf][2 + nf] = __builtin_amdgcn_mfma_f32_16x16x32_bf16(
                        af0[mf][ks], bf1[nf][ks], acc[mf][2 + nf], 0, 0, 0);
                }
            }
        __builtin_amdgcn_s_setprio(0);
        __builtin_amdgcn_s_barrier();

        // ======== Phase B: af1 reads; stage B(u+2) into cur ========
        #pragma unroll
        for (int mf = 0; mf < 4; ++mf)
            #pragma unroll
            for (int ks = 0; ks < 2; ++ks)
                af1[mf][ks] = rdA(cur, wm * 128 + 64 + mf * 16 + lr, ks);
        if (u + 2 < nkt) { stageu(cur, u + 2, 2); stageu(cur, u + 2, 3); }
        __builtin_amdgcn_s_barrier();
        asm volatile("s_waitcnt lgkmcnt(0)" ::: "memory");
        __builtin_amdgcn_sched_barrier(0);
        __builtin_amdgcn_s_setprio(1);
        #pragma unroll
        for (int mf = 0; mf < 4; ++mf)
            #pragma unroll
            for (int ks = 0; ks < 2; ++ks) {
                #pragma unroll
                for (int nf = 0; nf < 2; ++nf) {
                    acc[4 + mf][nf]     = __builtin_amdgcn_mfma_f32_16x16x32_bf16(
                        af1[mf][ks], bf0[nf][ks], acc[4 + mf][nf], 0, 0, 0);
                    acc[4 + mf][2 + nf] = __builtin_amdgcn_mfma_f32_16x16x32_bf16(
                        af1[mf][ks], bf1[nf][ks], acc[4 + mf][2 + nf], 0, 0, 0);
                }
            }
        __builtin_amdgcn_s_setprio(0);
        if (u + 2 < nkt) asm volatile("s_waitcnt vmcnt(4)" ::: "memory");
        else             asm volatile("s_waitcnt vmcnt(0)" ::: "memory");
        __builtin_amdgcn_sched_barrier(0);
        __builtin_amdgcn_s_barrier();
    }

    float*    Cf = (float*)Cv;
    ushort_t* Cb = (ushort_t*)Cv;
    #pragma unroll
    for (int mf = 0; mf < 8; ++mf) {
        int gm0 = m0 + wm * 128 + mf * 16 + lg * 4;
        #pragma unroll
        for (int nf = 0; nf < 4; ++nf) {
            int gn = n0 + wn * 64 + nf * 16 + lr;
            float bv = bias ? bias[gn] : 0.f;
            #pragma unroll
            for (int j = 0; j < 4; ++j) {
                float v = acc[mf][nf][j] + bv;
                if (GELU) v = gelu_f(v);
                size_t ci = (size_t)(gm0 + j) * ldc + gn;
                if (OUTBF) Cb[ci] = f2bf(v);
                else       Cf[ci] = v;
            }
        }
    }
}

// =====================================================================
// gemm_bt: 128xBNxBK64, 2-phase dbuf + 8-slot XOR swizzle. BN in {64,128}.
// BK=64 halves barrier count vs BK=32. XCD-chunked block swizzle.
// VOUT: for QKV, also scatter V columns (gn>=2048) into vt[BH][HD][S].
// r12 algebra: QKV@BN64 = -43us vs BN128 (3 blk/CU uniform fill wins).
// =====================================================================
template<int BN, bool GELU, bool RES, bool OUTBF, bool VOUT>
__global__ __launch_bounds__(256)
void gemm_bt(const ushort_t* __restrict__ A, int lda,
             const ushort_t* __restrict__ BT, int ldb,
             void* __restrict__ Cv, int ldc,
             const float* __restrict__ bias,
             const float* __restrict__ res,
             int M, int N, int K, ushort_t* __restrict__ vtp)
{
    const int BK = 64;
    const int NF = BN / 32;          // n-frags per wave
    int nwg = gridDim.x * gridDim.y;
    int id  = blockIdx.x + gridDim.x * blockIdx.y;
    int swz = ((nwg & 7) == 0) ? ((id & 7) * (nwg >> 3) + (id >> 3)) : id;
    int m0 = (swz % gridDim.x) * 128;
    int n0 = (swz / gridDim.x) * BN;

    __shared__ __align__(16) ushort_t lA[2][128 * BK];
    __shared__ __align__(16) ushort_t lB[2][BN * BK];

    int tid  = threadIdx.x;
    int lane = tid & 63;
    int wave = tid >> 6;
    int lr = lane & 15, lg = lane >> 4;
    int wr = wave >> 1, wc = wave & 1;

    f32x4 acc[4][NF] = {};
    int nkt = K / BK;

    auto stage = [&](int buf, int kt) {
        int k0 = kt * BK;
        #pragma unroll
        for (int i = 0; i < 4; ++i) {
            int e8  = i * 256 + tid;           // 16B units, 0..1023
            int row = e8 >> 3, slot = e8 & 7;
            int ls  = slot ^ (row & 7);
            const ushort_t* g = A + (size_t)(m0 + row) * lda + k0 + ls * 8;
            __builtin_amdgcn_global_load_lds(
                (const __attribute__((address_space(1))) void*)g,
                (__attribute__((address_space(3))) void*)&lA[buf][e8 * 8], 16, 0, 0);
        }
        #pragma unroll
        for (int i = 0; i < BN / 32; ++i) {
            int e8  = i * 256 + tid;
            int row = e8 >> 3, slot = e8 & 7;
            int ls  = slot ^ (row & 7);
            const ushort_t* g = BT + (size_t)(n0 + row) * ldb + k0 + ls * 8;
            __builtin_amdgcn_global_load_lds(
                (const __attribute__((address_space(1))) void*)g,
                (__attribute__((address_space(3))) void*)&lB[buf][e8 * 8], 16, 0, 0);
        }
    };

    stage(0, 0);
    __syncthreads();

    int cur = 0;
    for (int kt = 0; kt < nkt; ++kt) {
        if (kt + 1 < nkt) stage(cur ^ 1, kt + 1);
        __builtin_amdgcn_sched_barrier(0);
        s16x8 af[4][2], bfr[NF][2];
        #pragma unroll
        for (int m = 0; m < 4; ++m) {
            int row = wr * 64 + m * 16 + lr;
            #pragma unroll
            for (int ks = 0; ks < 2; ++ks) {
                int sl = (lg + ks * 4) ^ (row & 7);
                af[m][ks] = *(const s16x8*)&lA[cur][row * BK + sl * 8];
            }
        }
        #pragma unroll
        for (int n = 0; n < NF; ++n) {
            int row = wc * (BN / 2) + n * 16 + lr;
            #pragma unroll
            for (int ks = 0; ks < 2; ++ks) {
                int sl = (lg + ks * 4) ^ (row & 7);
                bfr[n][ks] = *(const s16x8*)&lB[cur][row * BK + sl * 8];
            }
        }
        __builtin_amdgcn_s_setprio(1);
        #pragma unroll
        for (int m = 0; m < 4; ++m)
            #pragma unroll
            for (int n = 0; n < NF; ++n)
                #pragma unroll
                for (int ks = 0; ks < 2; ++ks)
                    acc[m][n] = __builtin_amdgcn_mfma_f32_16x16x32_bf16(
                        af[m][ks], bfr[n][ks], acc[m][n], 0, 0, 0);
        __builtin_amdgcn_s_setprio(0);
        __syncthreads();
        cur ^= 1;
    }

    float*    Cf = (float*)Cv;
    ushort_t* Cb = (ushort_t*)Cv;
    #pragma unroll
    for (int m = 0; m < 4; ++m) {
        int gm0 = m0 + wr * 64 + m * 16 + lg * 4;
        #pragma unroll
        for (int n = 0; n < NF; ++n) {
            int gn = n0 + wc * (BN / 2) + n * 16 + lr;
            #pragma unroll
            for (int j = 0; j < 4; ++j) {
                float v = acc[m][n][j];
                if (bias) v += bias[gn];
                size_t ci = (size_t)(gm0 + j) * ldc + gn;
                if (RES)  v += res[ci];
                if (GELU) v = gelu_f(v);
                if (OUTBF) Cb[ci] = f2bf(v);
                else       Cf[ci] = v;
                if (VOUT && gn >= 2048) {
                    int hv = gn - 2048;
                    int mm = gm0 + j;
                    vtp[((size_t)(((mm >> 10) << 4) + (hv >> 6)) * 64
                         + (hv & 63)) * 1024 + (mm & 1023)] = f2bf(v);
                }
            }
        }
    }
}

// =====================================================================
// Flash attention, LOAD-BALANCED: grid (8, BH). Block x processes
// q-tiles {x, 15-x}: 17 KV-iters for EVERY block. K/V double-buffered
// with top-of-iter prefetch; setprio around MFMA clusters.
// =====================================================================
__global__ __launch_bounds__(256)
void flash_attn(const ushort_t* __restrict__ qkv,
                const ushort_t* __restrict__ vt,
                ushort_t* __restrict__ ctx)
{
    const int QB = 64, KB = 64;
    int z  = blockIdx.y;            // b*H + h
    int b  = z >> 4, hh = z & 15;

    __shared__ __align__(16) ushort_t Qs[QB * 64];
    __shared__ __align__(16) ushort_t Ks[2][KB * 64];
    __shared__ __align__(16) ushort_t Vs[2][64 * KB];
    __shared__ float    Ss[QB][68];
    __shared__ __align__(16) ushort_t Ps[QB][72];
    __shared__ float mrow[QB], lrow[QB], arow[QB];

    int tid  = threadIdx.x;
    int lane = tid & 63, wave = tid >> 6;
    int lr = lane & 15, lg = lane >> 4;
    int r = tid >> 2, p = tid & 3;

    auto stageKV = [&](int buf, int kv0) {
        const ushort_t* kbase = qkv + (size_t)(b * S_ + kv0) * 3072 + 1024 + hh * HD_;
        const ushort_t* vbase = vt + (size_t)z * HD_ * S_ + kv0;
        #pragma unroll
        for (int rnd = 0; rnd < 2; ++rnd) {
            int e8 = rnd * 256 + tid;
            int row = e8 >> 3, slot = e8 & 7;
            int ls = slot ^ (row & 7);
            const ushort_t* gk = kbase + (size_t)row * 3072 + ls * 8;
            __builtin_amdgcn_global_load_lds(
                (const __attribute__((address_space(1))) void*)gk,
                (__attribute__((address_space(3))) void*)&Ks[buf][e8 * 8], 16, 0, 0);
            const ushort_t* gv = vbase + (size_t)row * S_ + ls * 8;
            __builtin_amdgcn_global_load_lds(
                (const __attribute__((address_space(1))) void*)gv,
                (__attribute__((address_space(3))) void*)&Vs[buf][e8 * 8], 16, 0, 0);
        }
    };

    #pragma unroll
    for (int half = 0; half < 2; ++half) {
        int qt = half ? (15 - (int)blockIdx.x) : (int)blockIdx.x;
        int q0 = qt * QB;

        if (tid < QB) { mrow[tid] = -1e30f; lrow[tid] = 0.f; }
        const ushort_t* qbase = qkv + (size_t)(b * S_ + q0) * 3072 + hh * HD_;
        #pragma unroll
        for (int rnd = 0; rnd < 2; ++rnd) {
            int e8   = rnd * 256 + tid;
            int row  = e8 >> 3;
            int slot = e8 & 7;
            int ls   = slot ^ (row & 7);
            const ushort_t* g = qbase + (size_t)row * 3072 + ls * 8;
            __builtin_amdgcn_global_load_lds(
                (const __attribute__((address_space(1))) void*)g,
                (__attribute__((address_space(3))) void*)&Qs[e8 * 8], 16, 0, 0);
        }
        stageKV(0, 0);
        __syncthreads();

        s16x8 qa[4][2];
        #pragma unroll
        for (int mf = 0; mf < 4; ++mf)
            #pragma unroll
            for (int ks = 0; ks < 2; ++ks) {
                int row = mf * 16 + lr;
                int sl  = (lg + ks * 4) ^ (row & 7);
                qa[mf][ks] = *(const s16x8*)&Qs[row * 64 + sl * 8];
            }

        f32x4 acc[4] = {};
        int kv_end = q0 + QB;
        int cur = 0;
        for (int kv0 = 0; kv0 < kv_end; kv0 += KB) {
            if (kv0 + KB < kv_end) stageKV(cur ^ 1, kv0 + KB);

            s16x8 kb[2];
            #pragma unroll
            for (int ks = 0; ks < 2; ++ks) {
                int row = wave * 16 + lr;
                int sl  = (lg + ks * 4) ^ (row & 7);
                kb[ks] = *(const s16x8*)&Ks[cur][row * 64 + sl * 8];
            }
            f32x4 sa[4] = {};
            __builtin_amdgcn_s_setprio(1);
            #pragma unroll
            for (int mf = 0; mf < 4; ++mf)
                #pragma unroll
                for (int ks = 0; ks < 2; ++ks)
                    sa[mf] = __builtin_amdgcn_mfma_f32_16x16x32_bf16(
                        qa[mf][ks], kb[ks], sa[mf], 0, 0, 0);
            __builtin_amdgcn_s_setprio(0);

            int ki = kv0 + wave * 16 + lr;
            #pragma unroll
            for (int mf = 0; mf < 4; ++mf)
                #pragma unroll
                for (int j = 0; j < 4; ++j) {
                    int qi = q0 + mf * 16 + lg * 4 + j;
                    float s = (ki <= qi) ? sa[mf][j] * 0.125f : -1e30f;
                    Ss[mf * 16 + lg * 4 + j][wave * 16 + lr] = s;
                }
            __syncthreads();

            float mo = mrow[r];
            float sv[16];
            float pm = -1e30f;
            #pragma unroll
            for (int i = 0; i < 16; ++i) {
                sv[i] = Ss[r][p * 16 + i];
                pm = fmaxf(pm, sv[i]);
            }
            pm = fmaxf(pm, __shfl_xor(pm, 1, 64));
            pm = fmaxf(pm, __shfl_xor(pm, 2, 64));
            float M = fmaxf(mo, pm);
            float sum = 0.f;
            s16x8 pk0, pk1;
            #pragma unroll
            for (int i = 0; i < 8; ++i) {
                float e0 = __expf(sv[i] - M);
                float e1 = __expf(sv[i + 8] - M);
                sum += e0 + e1;
                pk0[i] = (short)f2bf(e0);
                pk1[i] = (short)f2bf(e1);
            }
            *(s16x8*)&Ps[r][p * 16]     = pk0;
            *(s16x8*)&Ps[r][p * 16 + 8] = pk1;
            sum += __shfl_xor(sum, 1, 64);
            sum += __shfl_xor(sum, 2, 64);
            if (p == 0) {
                float al = __expf(mo - M);
                arow[r] = al;
                mrow[r] = M;
                lrow[r] = lrow[r] * al + sum;
            }
            __syncthreads();

            #pragma unroll
            for (int mf = 0; mf < 4; ++mf) {
                #pragma unroll
                for (int j = 0; j < 4; ++j)
                    acc[mf][j] *= arow[mf * 16 + lg * 4 + j];
            }
            s16x8 vb[2];
            #pragma unroll
            for (int ks = 0; ks < 2; ++ks) {
                int row = wave * 16 + lr;
                int sl  = (lg + ks * 4) ^ (row & 7);
                vb[ks] = *(const s16x8*)&Vs[cur][row * 64 + sl * 8];
            }
            __builtin_amdgcn_s_setprio(1);
            #pragma unroll
            for (int mf = 0; mf < 4; ++mf)
                #pragma unroll
                for (int ks = 0; ks < 2; ++ks) {
                    s16x8 pa = *(const s16x8*)((const char*)&Ps[0][0]
                                + (mf * 16 + lr) * 144 + lg * 16 + ks * 64);
                    acc[mf] = __builtin_amdgcn_mfma_f32_16x16x32_bf16(
                        pa, vb[ks], acc[mf], 0, 0, 0);
                }
            __builtin_amdgcn_s_setprio(0);
            __syncthreads();
            cur ^= 1;
        }

        #pragma unroll
        for (int mf = 0; mf < 4; ++mf)
            #pragma unroll
            for (int j = 0; j < 4; ++j) {
                int rr = mf * 16 + lg * 4 + j;
                float o = acc[mf][j] / lrow[rr];
                ctx[(size_t)(b * S_ + q0 + rr) * D_ + hh * HD_ + wave * 16 + lr] = f2bf(o);
            }
        __syncthreads();   // protect Qs/Ks/Vs/state before next half
    }
}

// =====================================================================
// prep_layer: ONE layer's weight transposes+converts + qkv bias concat.
// Per-layer (not up-front!): r12 algebra showed up-front conversion of
// all layers costs +162us — per-layer keeps converted weights L2/LLC-hot
// for the immediately-following GEMMs. 3075 blocks.
// =====================================================================
#define DD_ (D_*D_)
#define DF_ (D_*F_)
#define WL_ (3*DD_ + DD_ + DF_ + DF_)
__global__ __launch_bounds__(256)
void prep_layer(const float* __restrict__ Wq, const float* __restrict__ Wk,
                const float* __restrict__ Wv, const float* __restrict__ Wo,
                const float* __restrict__ W1, const float* __restrict__ W2,
                const float* __restrict__ bq, const float* __restrict__ bk,
                const float* __restrict__ bv,
                ushort_t* __restrict__ wl, float* __restrict__ qkvb)
{
    int bid = blockIdx.x;
    __shared__ float t[64][65];
    int tid = threadIdx.x;
    int tx = tid & 63, ty = tid >> 6;
    const float* src; ushort_t* dst; int R, C, c0, r0;

    if (bid >= 3072) {
        int j = bid - 3072;
        const float* bsrc = (j == 0) ? bq : (j == 1) ? bk : bv;
        int c = tid * 4;
        *(f32x4*)&qkvb[j * 1024 + c] = *(const f32x4*)&bsrc[c];
        return;
    }
    if (bid < 1024) {
        int mat = bid >> 8, tnum = bid & 255;
        src = (mat == 0) ? Wq : (mat == 1) ? Wk : (mat == 2) ? Wv : Wo;
        dst = (mat < 3) ? (wl + (size_t)mat * DD_) : (wl + 3 * (size_t)DD_);
        R = D_; C = D_;
        c0 = (tnum & 15) * 64; r0 = (tnum >> 4) * 64;
    } else if (bid < 2048) {
        int tnum = bid - 1024;
        src = W1; dst = wl + 4 * (size_t)DD_;
        R = D_; C = F_;
        c0 = (tnum & 63) * 64; r0 = (tnum >> 6) * 64;
    } else {
        int tnum = bid - 2048;
        src = W2; dst = wl + 4 * (size_t)DD_ + (size_t)DF_;
        R = F_; C = D_;
        c0 = (tnum & 15) * 64; r0 = (tnum >> 4) * 64;
    }
    #pragma unroll
    for (int i = 0; i < 16; ++i)
        t[ty + i * 4][tx] = src[(size_t)(r0 + ty + i * 4) * C + c0 + tx];
    __syncthreads();
    int u = tid & 31, v = tid >> 5;
    #pragma unroll
    for (int i = 0; i < 8; ++i) {
        int cc = v + i * 8;
        unsigned int val = (unsigned int)f2bf(t[u * 2][cc])
                         | ((unsigned int)f2bf(t[u * 2 + 1][cc]) << 16);
        *(unsigned int*)&dst[(size_t)(c0 + cc) * R + r0 + u * 2] = val;
    }
}

// ---- f32 [R,C] -> bf16 [C,R] transpose-convert, 64x64 tiles (Wout) ----
__global__ __launch_bounds__(256)
void tconv(const float* __restrict__ in, ushort_t* __restrict__ out, int R, int C)
{
    __shared__ float t[64][65];
    int c0 = blockIdx.x * 64, r0 = blockIdx.y * 64;
    int tid = threadIdx.x;
    int tx = tid & 63, ty = tid >> 6;
    #pragma unroll
    for (int i = 0; i < 16; ++i)
        t[ty + i * 4][tx] = in[(size_t)(r0 + ty + i * 4) * C + c0 + tx];
    __syncthreads();
    int u = tid & 31, v = tid >> 5;
    #pragma unroll
    for (int i = 0; i < 8; ++i) {
        int cc = v + i * 8;
        unsigned int val = (unsigned int)f2bf(t[u * 2][cc])
                         | ((unsigned int)f2bf(t[u * 2 + 1][cc]) << 16);
        *(unsigned int*)&out[(size_t)(c0 + cc) * R + r0 + u * 2] = val;
    }
}

// ---- embedding * sqrt(D) + sinusoidal PE -> x (f32) ----
__global__ __launch_bounds__(256)
void embed_pe(const int* __restrict__ ids, const float* __restrict__ emb,
              float* __restrict__ x)
{
    int row = blockIdx.x;
    int s   = row & (S_ - 1);
    int id  = ids[row];
    int d   = threadIdx.x * 4;
    f32x4 ev = *(const f32x4*)&emb[(size_t)id * D_ + d];
    f32x4 o;
    #pragma unroll
    for (int j = 0; j < 4; ++j) {
        int dd = d + j;
        int i  = dd >> 1;
        float div = expf(-(float)(2 * i) * (9.210340371976184f / 1024.0f));
        float arg = (float)s * div;
        float pe  = (dd & 1) ? cosf(arg) : sinf(arg);
        o[j] = ev[j] * 32.0f + pe;
    }
    *(f32x4*)&x[(size_t)row * D_ + d] = o;
}

// ---- LayerNorm row kernel: f32 in -> bf16 out ----
__global__ __launch_bounds__(256)
void ln_kernel(const float* __restrict__ x, const float* __restrict__ g,
               const float* __restrict__ b, ushort_t* __restrict__ out)
{
    __shared__ float sb[4];
    int row = blockIdx.x;
    const float* xr = x + (size_t)row * D_;
    int c = threadIdx.x * 4;
    f32x4 v = *(const f32x4*)&xr[c];
    float s = v[0] + v[1] + v[2] + v[3];
    s = blk_sum(s, sb);
    float mean = s * (1.0f / D_);
    f32x4 dv = v - mean;
    float sq = dv[0]*dv[0] + dv[1]*dv[1] + dv[2]*dv[2] + dv[3]*dv[3];
    sq = blk_sum(sq, sb);
    float rstd = rsqrtf(sq * (1.0f / D_) + EPSLN);
    u16x4 o;
    #pragma unroll
    for (int j = 0; j < 4; ++j)
        o[j] = f2bf(dv[j] * rstd * g[c + j] + b[c + j]);
    *(u16x4*)&out[(size_t)row * D_ + c] = o;
}

__global__ void ws_marker(float* o) { o[threadIdx.x] = -777777.0f; }

// =====================================================================
extern "C" void kernel_launch(void* const* d_in, const int* in_sizes, int n_in,
                              void* d_out, int out_size, void* d_ws, size_t ws_size,
                              hipStream_t stream)
{
    (void)in_sizes; (void)n_in; (void)out_size;
    const int*   ids  = (const int*)d_in[0];
    const float* emb  = (const float*)d_in[1];
    const float* Wq   = (const float*)d_in[2];
    const float* bq   = (const float*)d_in[3];
    const float* Wk   = (const float*)d_in[4];
    const float* bk   = (const float*)d_in[5];
    const float* Wv   = (const float*)d_in[6];
    const float* bv   = (const float*)d_in[7];
    const float* Wo   = (const float*)d_in[8];
    const float* bo   = (const float*)d_in[9];
    const float* ln1g = (const float*)d_in[10];
    const float* ln1b = (const float*)d_in[11];
    const float* ln2g = (const float*)d_in[12];
    const float* ln2b = (const float*)d_in[13];
    const float* W1   = (const float*)d_in[14];
    const float* b1   = (const float*)d_in[15];
    const float* W2   = (const float*)d_in[16];
    const float* b2   = (const float*)d_in[17];
    const float* fng  = (const float*)d_in[18];
    const float* fnb  = (const float*)d_in[19];
    const float* Wout = (const float*)d_in[20];
    const float* bout = (const float*)d_in[21];
    float* out = (float*)d_out;

    // ---- workspace layout ----
    char* base = (char*)d_ws;
    size_t off = 0;
    float*    x    = (float*)(base + off);    off += (size_t)MTOK * D_ * 4;
    ushort_t* h    = (ushort_t*)(base + off); off += (size_t)MTOK * D_ * 2;
    ushort_t* qkv  = (ushort_t*)(base + off); off += (size_t)MTOK * 3 * D_ * 2;
    ushort_t* vt   = (ushort_t*)(base + off); off += (size_t)B_ * H_ * HD_ * S_ * 2;
    ushort_t* ctx  = (ushort_t*)(base + off); off += (size_t)MTOK * D_ * 2;
    ushort_t* ff   = (ushort_t*)(base + off); off += (size_t)MTOK * F_ * 2;
    float*    qkvb = (float*)(base + off);    off += 3072 * 4;
    ushort_t* wouT = (ushort_t*)(base + off); off += (size_t)V_ * D_ * 2;
    ushort_t* wl   = (ushort_t*)(base + off); off += (size_t)WL_ * 2;
    if (ws_size < off) { ws_marker<<<1, 64, 0, stream>>>(out); return; }

    ushort_t* wqkvT = wl;
    ushort_t* woT   = wl + 3 * (size_t)DD_;
    ushort_t* w1T   = wl + 4 * (size_t)DD_;
    ushort_t* w2T   = wl + 4 * (size_t)DD_ + (size_t)DF_;

    embed_pe<<<MTOK, 256, 0, stream>>>(ids, emb, x);

    for (int i = 0; i < L_; ++i) {
        // per-layer prep: converted weights stay cache-hot for this layer
        prep_layer<<<3075, 256, 0, stream>>>(
            Wq + (size_t)i * DD_, Wk + (size_t)i * DD_,
            Wv + (size_t)i * DD_, Wo + (size_t)i * DD_,
            W1 + (size_t)i * DF_, W2 + (size_t)i * DF_,
            bq + i * D_, bk + i * D_, bv + i * D_, wl, qkvb);

        ln_kernel<<<MTOK, 256, 0, stream>>>(x, ln1g + i * D_, ln1b + i * D_, h);

        // qkv = h @ [Wq|Wk|Wv] + bias; V cols also scattered into vt
        // BN=64 -> 768 blocks @48KB = 3 blk/CU uniform (r12 algebra: -43us)
        gemm_bt<64,false,false,true,true><<<dim3(16, 48), 256, 0, stream>>>(
            h, D_, wqkvT, D_, qkv, 3 * D_, qkvb, nullptr, MTOK, 3 * D_, D_, vt);

        flash_attn<<<dim3(8, B_ * H_), 256, 0, stream>>>(qkv, vt, ctx);

        // x = x + ctx @ Wo + bo
        gemm_bt<64,false,true,false,false><<<dim3(16, 16), 256, 0, stream>>>(
            ctx, D_, woT, D_, x, D_, bo + i * D_, x, MTOK, D_, D_, nullptr);

        ln_kernel<<<MTOK, 256, 0, stream>>>(x, ln2g + i * D_, ln2b + i * D_, h);

        // ff = gelu(h @ W1 + b1)
        gemm_bt<128,true,false,true,false><<<dim3(16, 32), 256, 0, stream>>>(
            h, D_, w1T, D_, ff, F_, b1 + i * F_, nullptr, MTOK, F_, D_, nullptr);

        // x = x + ff @ W2 + b2
        gemm_bt<64,false,true,false,false><<<dim3(16, 16), 256, 0, stream>>>(
            ff, F_, w2T, F_, x, D_, b2 + i * D_, x, MTOK, D_, F_, nullptr);
    }

    ln_kernel<<<MTOK, 256, 0, stream>>>(x, fng, fnb, h);
    tconv<<<dim3(500, 16), 256, 0, stream>>>(Wout, wouT, D_, V_);
    // logits: 256^2 tiles (measured-best for N=32000)
    gemm256<false,false><<<dim3(8, 125), 512, 0, stream>>>(
        h, D_, wouT, D_, out, V_, bout, MTOK, V_, D_);
}

// Round 14
// 1422.132 us; speedup vs baseline: 1.1531x; 1.0083x over previous
//
#include <hip/hip_runtime.h>
#include <math.h>

// ---- problem constants ----
#define V_   32000
#define D_   1024
#define H_   16
#define HD_  64
#define L_   6
#define F_   4096
#define S_   1024
#define B_   2
#define MTOK (B_*S_)      // 2048
#define EPSLN 1e-5f

typedef unsigned short ushort_t;
typedef __attribute__((ext_vector_type(8))) short  s16x8;
typedef __attribute__((ext_vector_type(4))) float  f32x4;
typedef __attribute__((ext_vector_type(4))) unsigned short u16x4;

__device__ __forceinline__ float bf2f(unsigned short u) {
    unsigned int x = ((unsigned int)u) << 16;
    return __builtin_bit_cast(float, x);
}
__device__ __forceinline__ unsigned short f2bf(float f) {
    unsigned int x = __builtin_bit_cast(unsigned int, f);
    unsigned int r = (x + 0x7FFFu + ((x >> 16) & 1u)) >> 16;   // RNE
    return (unsigned short)r;
}
__device__ __forceinline__ float gelu_f(float x) {
    float y = 0.7978845608f * (x + 0.044715f * x * x * x);
    float t = 1.0f - 2.0f / (__expf(2.0f * y) + 1.0f);
    return 0.5f * x * (1.0f + t);
}

__device__ __forceinline__ float blk_sum(float v, float* sb) {
    #pragma unroll
    for (int o = 32; o; o >>= 1) v += __shfl_xor(v, o, 64);
    int w = threadIdx.x >> 6;
    __syncthreads();
    if ((threadIdx.x & 63) == 0) sb[w] = v;
    __syncthreads();
    return sb[0] + sb[1] + sb[2] + sb[3];
}

// =====================================================================
// gemm256: 2-phase-per-K-tile pipelined 256x256xBK64 bf16 MFMA GEMM.
// Measured-best for the N=32000 logits shape (177us, 740 TF).
// =====================================================================
template<bool GELU, bool OUTBF>
__global__ __launch_bounds__(512, 2)
void gemm256(const ushort_t* __restrict__ A, int lda,
             const ushort_t* __restrict__ BT, int ldb,
             void* __restrict__ Cv, int ldc,
             const float* __restrict__ bias,
             int M, int N, int K)
{
    int nmt = M >> 8;
    int nwg = gridDim.x * gridDim.y;
    int id  = blockIdx.x + gridDim.x * blockIdx.y;
    int swz = ((nwg & 7) == 0) ? ((id & 7) * (nwg >> 3) + (id >> 3)) : id;
    int m0 = (swz % nmt) << 8;
    int n0 = (swz / nmt) << 8;

    __shared__ __align__(16) ushort_t lA[2][256 * 64];
    __shared__ __align__(16) ushort_t lB[2][256 * 64];

    int tid  = threadIdx.x;
    int lane = tid & 63, wave = tid >> 6;
    int lr = lane & 15, lg = lane >> 4;
    int wm = wave >> 2, wn = wave & 3;

    f32x4 acc[8][4] = {};
    int nkt = K >> 6;

    auto stageu = [&](int buf, int kt, int sel) {
        int k0 = kt << 6;
        const ushort_t* src = (sel < 2) ? A : BT;
        int ld    = (sel < 2) ? lda : ldb;
        int rbase = ((sel < 2) ? m0 : n0) + ((sel & 1) << 7);
        ushort_t* dst = ((sel < 2) ? &lA[buf][0] : &lB[buf][0]) + ((sel & 1) << 13);
        #pragma unroll
        for (int r = 0; r < 2; ++r) {
            int e8  = r * 512 + tid;
            int row = e8 >> 3, slot = e8 & 7;
            int ls  = slot ^ (row & 7);
            const ushort_t* g = src + (size_t)(rbase + row) * ld + k0 + ls * 8;
            __builtin_amdgcn_global_load_lds(
                (const __attribute__((address_space(1))) void*)g,
                (__attribute__((address_space(3))) void*)(dst + e8 * 8), 16, 0, 0);
        }
    };
    auto rdA = [&](int buf, int row, int ks) -> s16x8 {
        int sl = (lg + ks * 4) ^ (row & 7);
        return *(const s16x8*)&lA[buf][row * 64 + sl * 8];
    };
    auto rdB = [&](int buf, int row, int ks) -> s16x8 {
        int sl = (lg + ks * 4) ^ (row & 7);
        return *(const s16x8*)&lB[buf][row * 64 + sl * 8];
    };

    stageu(0, 0, 0); stageu(0, 0, 1); stageu(0, 0, 2); stageu(0, 0, 3);
    if (nkt > 1) {
        stageu(1, 1, 2); stageu(1, 1, 3);
        asm volatile("s_waitcnt vmcnt(4)" ::: "memory");
    } else {
        asm volatile("s_waitcnt vmcnt(0)" ::: "memory");
    }
    __builtin_amdgcn_sched_barrier(0);
    __builtin_amdgcn_s_barrier();

    for (int u = 0; u < nkt; ++u) {
        int cur = u & 1, nxt = cur ^ 1;
        s16x8 af0[4][2], af1[4][2], bf0[2][2], bf1[2][2];

        // ======== Phase A: af0 + bf0 + bf1 reads; stage A(u+1) ========
        #pragma unroll
        for (int mf = 0; mf < 4; ++mf)
            #pragma unroll
            for (int ks = 0; ks < 2; ++ks)
                af0[mf][ks] = rdA(cur, wm * 128 + mf * 16 + lr, ks);
        #pragma unroll
        for (int nf = 0; nf < 2; ++nf)
            #pragma unroll
            for (int ks = 0; ks < 2; ++ks) {
                bf0[nf][ks] = rdB(cur, wn * 64 + nf * 16 + lr, ks);
                bf1[nf][ks] = rdB(cur, wn * 64 + 32 + nf * 16 + lr, ks);
            }
        if (u + 1 < nkt) { stageu(nxt, u + 1, 0); stageu(nxt, u + 1, 1); }
        __builtin_amdgcn_s_barrier();
        asm volatile("s_waitcnt lgkmcnt(0)" ::: "memory");
        __builtin_amdgcn_sched_barrier(0);
        __builtin_amdgcn_s_setprio(1);
        #pragma unroll
        for (int mf = 0; mf < 4; ++mf)
            #pragma unroll
            for (int ks = 0; ks < 2; ++ks) {
                #pragma unroll
                for (int nf = 0; nf < 2; ++nf) {
                    acc[mf][nf]     = __builtin_amdgcn_mfma_f32_16x16x32_bf16(
                        af0[mf][ks], bf0[nf][ks], acc[mf][nf], 0, 0, 0);
                    acc[mf][2 + nf] = __builtin_amdgcn_mfma_f32_16x16x32_bf16(
                        af0[mf][ks], bf1[nf][ks], acc[mf][2 + nf], 0, 0, 0);
                }
            }
        __builtin_amdgcn_s_setprio(0);
        __builtin_amdgcn_s_barrier();

        // ======== Phase B: af1 reads; stage B(u+2) into cur ========
        #pragma unroll
        for (int mf = 0; mf < 4; ++mf)
            #pragma unroll
            for (int ks = 0; ks < 2; ++ks)
                af1[mf][ks] = rdA(cur, wm * 128 + 64 + mf * 16 + lr, ks);
        if (u + 2 < nkt) { stageu(cur, u + 2, 2); stageu(cur, u + 2, 3); }
        __builtin_amdgcn_s_barrier();
        asm volatile("s_waitcnt lgkmcnt(0)" ::: "memory");
        __builtin_amdgcn_sched_barrier(0);
        __builtin_amdgcn_s_setprio(1);
        #pragma unroll
        for (int mf = 0; mf < 4; ++mf)
            #pragma unroll
            for (int ks = 0; ks < 2; ++ks) {
                #pragma unroll
                for (int nf = 0; nf < 2; ++nf) {
                    acc[4 + mf][nf]     = __builtin_amdgcn_mfma_f32_16x16x32_bf16(
                        af1[mf][ks], bf0[nf][ks], acc[4 + mf][nf], 0, 0, 0);
                    acc[4 + mf][2 + nf] = __builtin_amdgcn_mfma_f32_16x16x32_bf16(
                        af1[mf][ks], bf1[nf][ks], acc[4 + mf][2 + nf], 0, 0, 0);
                }
            }
        __builtin_amdgcn_s_setprio(0);
        if (u + 2 < nkt) asm volatile("s_waitcnt vmcnt(4)" ::: "memory");
        else             asm volatile("s_waitcnt vmcnt(0)" ::: "memory");
        __builtin_amdgcn_sched_barrier(0);
        __builtin_amdgcn_s_barrier();
    }

    float*    Cf = (float*)Cv;
    ushort_t* Cb = (ushort_t*)Cv;
    #pragma unroll
    for (int mf = 0; mf < 8; ++mf) {
        int gm0 = m0 + wm * 128 + mf * 16 + lg * 4;
        #pragma unroll
        for (int nf = 0; nf < 4; ++nf) {
            int gn = n0 + wn * 64 + nf * 16 + lr;
            float bv = bias ? bias[gn] : 0.f;
            #pragma unroll
            for (int j = 0; j < 4; ++j) {
                float v = acc[mf][nf][j] + bv;
                if (GELU) v = gelu_f(v);
                size_t ci = (size_t)(gm0 + j) * ldc + gn;
                if (OUTBF) Cb[ci] = f2bf(v);
                else       Cf[ci] = v;
            }
        }
    }
}

// =====================================================================
// gemm_bt: 128xBNxBK64, 2-phase dbuf + 8-slot XOR swizzle. BN in {64,128}.
// BK=64 halves barrier count vs BK=32. XCD-chunked block swizzle.
// VOUT: for QKV, also scatter V columns (gn>=2048) into vt[BH][HD][S].
// =====================================================================
template<int BN, bool GELU, bool RES, bool OUTBF, bool VOUT>
__global__ __launch_bounds__(256)
void gemm_bt(const ushort_t* __restrict__ A, int lda,
             const ushort_t* __restrict__ BT, int ldb,
             void* __restrict__ Cv, int ldc,
             const float* __restrict__ bias,
             const float* __restrict__ res,
             int M, int N, int K, ushort_t* __restrict__ vtp)
{
    const int BK = 64;
    const int NF = BN / 32;          // n-frags per wave
    int nwg = gridDim.x * gridDim.y;
    int id  = blockIdx.x + gridDim.x * blockIdx.y;
    int swz = ((nwg & 7) == 0) ? ((id & 7) * (nwg >> 3) + (id >> 3)) : id;
    int m0 = (swz % gridDim.x) * 128;
    int n0 = (swz / gridDim.x) * BN;

    __shared__ __align__(16) ushort_t lA[2][128 * BK];
    __shared__ __align__(16) ushort_t lB[2][BN * BK];

    int tid  = threadIdx.x;
    int lane = tid & 63;
    int wave = tid >> 6;
    int lr = lane & 15, lg = lane >> 4;
    int wr = wave >> 1, wc = wave & 1;

    f32x4 acc[4][NF] = {};
    int nkt = K / BK;

    auto stage = [&](int buf, int kt) {
        int k0 = kt * BK;
        #pragma unroll
        for (int i = 0; i < 4; ++i) {
            int e8  = i * 256 + tid;           // 16B units, 0..1023
            int row = e8 >> 3, slot = e8 & 7;
            int ls  = slot ^ (row & 7);
            const ushort_t* g = A + (size_t)(m0 + row) * lda + k0 + ls * 8;
            __builtin_amdgcn_global_load_lds(
                (const __attribute__((address_space(1))) void*)g,
                (__attribute__((address_space(3))) void*)&lA[buf][e8 * 8], 16, 0, 0);
        }
        #pragma unroll
        for (int i = 0; i < BN / 32; ++i) {
            int e8  = i * 256 + tid;
            int row = e8 >> 3, slot = e8 & 7;
            int ls  = slot ^ (row & 7);
            const ushort_t* g = BT + (size_t)(n0 + row) * ldb + k0 + ls * 8;
            __builtin_amdgcn_global_load_lds(
                (const __attribute__((address_space(1))) void*)g,
                (__attribute__((address_space(3))) void*)&lB[buf][e8 * 8], 16, 0, 0);
        }
    };

    stage(0, 0);
    __syncthreads();

    int cur = 0;
    for (int kt = 0; kt < nkt; ++kt) {
        if (kt + 1 < nkt) stage(cur ^ 1, kt + 1);
        __builtin_amdgcn_sched_barrier(0);
        s16x8 af[4][2], bfr[NF][2];
        #pragma unroll
        for (int m = 0; m < 4; ++m) {
            int row = wr * 64 + m * 16 + lr;
            #pragma unroll
            for (int ks = 0; ks < 2; ++ks) {
                int sl = (lg + ks * 4) ^ (row & 7);
                af[m][ks] = *(const s16x8*)&lA[cur][row * BK + sl * 8];
            }
        }
        #pragma unroll
        for (int n = 0; n < NF; ++n) {
            int row = wc * (BN / 2) + n * 16 + lr;
            #pragma unroll
            for (int ks = 0; ks < 2; ++ks) {
                int sl = (lg + ks * 4) ^ (row & 7);
                bfr[n][ks] = *(const s16x8*)&lB[cur][row * BK + sl * 8];
            }
        }
        __builtin_amdgcn_s_setprio(1);
        #pragma unroll
        for (int m = 0; m < 4; ++m)
            #pragma unroll
            for (int n = 0; n < NF; ++n)
                #pragma unroll
                for (int ks = 0; ks < 2; ++ks)
                    acc[m][n] = __builtin_amdgcn_mfma_f32_16x16x32_bf16(
                        af[m][ks], bfr[n][ks], acc[m][n], 0, 0, 0);
        __builtin_amdgcn_s_setprio(0);
        __syncthreads();
        cur ^= 1;
    }

    float*    Cf = (float*)Cv;
    ushort_t* Cb = (ushort_t*)Cv;
    #pragma unroll
    for (int m = 0; m < 4; ++m) {
        int gm0 = m0 + wr * 64 + m * 16 + lg * 4;
        #pragma unroll
        for (int n = 0; n < NF; ++n) {
            int gn = n0 + wc * (BN / 2) + n * 16 + lr;
            #pragma unroll
            for (int j = 0; j < 4; ++j) {
                float v = acc[m][n][j];
                if (bias) v += bias[gn];
                size_t ci = (size_t)(gm0 + j) * ldc + gn;
                if (RES)  v += res[ci];
                if (GELU) v = gelu_f(v);
                if (OUTBF) Cb[ci] = f2bf(v);
                else       Cf[ci] = v;
                if (VOUT && gn >= 2048) {
                    int hv = gn - 2048;
                    int mm = gm0 + j;
                    vtp[((size_t)(((mm >> 10) << 4) + (hv >> 6)) * 64
                         + (hv & 63)) * 1024 + (mm & 1023)] = f2bf(v);
                }
            }
        }
    }
}

// =====================================================================
// Flash attention, LOAD-BALANCED: grid (8, BH). Block x processes
// q-tiles {x, 15-x}: 17 KV-iters for EVERY block. K/V double-buffered
// with top-of-iter prefetch; setprio around MFMA clusters.
// =====================================================================
__global__ __launch_bounds__(256)
void flash_attn(const ushort_t* __restrict__ qkv,
                const ushort_t* __restrict__ vt,
                ushort_t* __restrict__ ctx)
{
    const int QB = 64, KB = 64;
    int z  = blockIdx.y;            // b*H + h
    int b  = z >> 4, hh = z & 15;

    __shared__ __align__(16) ushort_t Qs[QB * 64];
    __shared__ __align__(16) ushort_t Ks[2][KB * 64];
    __shared__ __align__(16) ushort_t Vs[2][64 * KB];
    __shared__ float    Ss[QB][68];
    __shared__ __align__(16) ushort_t Ps[QB][72];
    __shared__ float mrow[QB], lrow[QB], arow[QB];

    int tid  = threadIdx.x;
    int lane = tid & 63, wave = tid >> 6;
    int lr = lane & 15, lg = lane >> 4;
    int r = tid >> 2, p = tid & 3;

    auto stageKV = [&](int buf, int kv0) {
        const ushort_t* kbase = qkv + (size_t)(b * S_ + kv0) * 3072 + 1024 + hh * HD_;
        const ushort_t* vbase = vt + (size_t)z * HD_ * S_ + kv0;
        #pragma unroll
        for (int rnd = 0; rnd < 2; ++rnd) {
            int e8 = rnd * 256 + tid;
            int row = e8 >> 3, slot = e8 & 7;
            int ls = slot ^ (row & 7);
            const ushort_t* gk = kbase + (size_t)row * 3072 + ls * 8;
            __builtin_amdgcn_global_load_lds(
                (const __attribute__((address_space(1))) void*)gk,
                (__attribute__((address_space(3))) void*)&Ks[buf][e8 * 8], 16, 0, 0);
            const ushort_t* gv = vbase + (size_t)row * S_ + ls * 8;
            __builtin_amdgcn_global_load_lds(
                (const __attribute__((address_space(1))) void*)gv,
                (__attribute__((address_space(3))) void*)&Vs[buf][e8 * 8], 16, 0, 0);
        }
    };

    #pragma unroll
    for (int half = 0; half < 2; ++half) {
        int qt = half ? (15 - (int)blockIdx.x) : (int)blockIdx.x;
        int q0 = qt * QB;

        if (tid < QB) { mrow[tid] = -1e30f; lrow[tid] = 0.f; }
        const ushort_t* qbase = qkv + (size_t)(b * S_ + q0) * 3072 + hh * HD_;
        #pragma unroll
        for (int rnd = 0; rnd < 2; ++rnd) {
            int e8   = rnd * 256 + tid;
            int row  = e8 >> 3;
            int slot = e8 & 7;
            int ls   = slot ^ (row & 7);
            const ushort_t* g = qbase + (size_t)row * 3072 + ls * 8;
            __builtin_amdgcn_global_load_lds(
                (const __attribute__((address_space(1))) void*)g,
                (__attribute__((address_space(3))) void*)&Qs[e8 * 8], 16, 0, 0);
        }
        stageKV(0, 0);
        __syncthreads();

        s16x8 qa[4][2];
        #pragma unroll
        for (int mf = 0; mf < 4; ++mf)
            #pragma unroll
            for (int ks = 0; ks < 2; ++ks) {
                int row = mf * 16 + lr;
                int sl  = (lg + ks * 4) ^ (row & 7);
                qa[mf][ks] = *(const s16x8*)&Qs[row * 64 + sl * 8];
            }

        f32x4 acc[4] = {};
        int kv_end = q0 + QB;
        int cur = 0;
        for (int kv0 = 0; kv0 < kv_end; kv0 += KB) {
            if (kv0 + KB < kv_end) stageKV(cur ^ 1, kv0 + KB);

            s16x8 kb[2];
            #pragma unroll
            for (int ks = 0; ks < 2; ++ks) {
                int row = wave * 16 + lr;
                int sl  = (lg + ks * 4) ^ (row & 7);
                kb[ks] = *(const s16x8*)&Ks[cur][row * 64 + sl * 8];
            }
            f32x4 sa[4] = {};
            __builtin_amdgcn_s_setprio(1);
            #pragma unroll
            for (int mf = 0; mf < 4; ++mf)
                #pragma unroll
                for (int ks = 0; ks < 2; ++ks)
                    sa[mf] = __builtin_amdgcn_mfma_f32_16x16x32_bf16(
                        qa[mf][ks], kb[ks], sa[mf], 0, 0, 0);
            __builtin_amdgcn_s_setprio(0);

            int ki = kv0 + wave * 16 + lr;
            #pragma unroll
            for (int mf = 0; mf < 4; ++mf)
                #pragma unroll
                for (int j = 0; j < 4; ++j) {
                    int qi = q0 + mf * 16 + lg * 4 + j;
                    float s = (ki <= qi) ? sa[mf][j] * 0.125f : -1e30f;
                    Ss[mf * 16 + lg * 4 + j][wave * 16 + lr] = s;
                }
            __syncthreads();

            float mo = mrow[r];
            float sv[16];
            float pm = -1e30f;
            #pragma unroll
            for (int i = 0; i < 16; ++i) {
                sv[i] = Ss[r][p * 16 + i];
                pm = fmaxf(pm, sv[i]);
            }
            pm = fmaxf(pm, __shfl_xor(pm, 1, 64));
            pm = fmaxf(pm, __shfl_xor(pm, 2, 64));
            float M = fmaxf(mo, pm);
            float sum = 0.f;
            s16x8 pk0, pk1;
            #pragma unroll
            for (int i = 0; i < 8; ++i) {
                float e0 = __expf(sv[i] - M);
                float e1 = __expf(sv[i + 8] - M);
                sum += e0 + e1;
                pk0[i] = (short)f2bf(e0);
                pk1[i] = (short)f2bf(e1);
            }
            *(s16x8*)&Ps[r][p * 16]     = pk0;
            *(s16x8*)&Ps[r][p * 16 + 8] = pk1;
            sum += __shfl_xor(sum, 1, 64);
            sum += __shfl_xor(sum, 2, 64);
            if (p == 0) {
                float al = __expf(mo - M);
                arow[r] = al;
                mrow[r] = M;
                lrow[r] = lrow[r] * al + sum;
            }
            __syncthreads();

            #pragma unroll
            for (int mf = 0; mf < 4; ++mf) {
                #pragma unroll
                for (int j = 0; j < 4; ++j)
                    acc[mf][j] *= arow[mf * 16 + lg * 4 + j];
            }
            s16x8 vb[2];
            #pragma unroll
            for (int ks = 0; ks < 2; ++ks) {
                int row = wave * 16 + lr;
                int sl  = (lg + ks * 4) ^ (row & 7);
                vb[ks] = *(const s16x8*)&Vs[cur][row * 64 + sl * 8];
            }
            __builtin_amdgcn_s_setprio(1);
            #pragma unroll
            for (int mf = 0; mf < 4; ++mf)
                #pragma unroll
                for (int ks = 0; ks < 2; ++ks) {
                    s16x8 pa = *(const s16x8*)((const char*)&Ps[0][0]
                                + (mf * 16 + lr) * 144 + lg * 16 + ks * 64);
                    acc[mf] = __builtin_amdgcn_mfma_f32_16x16x32_bf16(
                        pa, vb[ks], acc[mf], 0, 0, 0);
                }
            __builtin_amdgcn_s_setprio(0);
            __syncthreads();
            cur ^= 1;
        }

        #pragma unroll
        for (int mf = 0; mf < 4; ++mf)
            #pragma unroll
            for (int j = 0; j < 4; ++j) {
                int rr = mf * 16 + lg * 4 + j;
                float o = acc[mf][j] / lrow[rr];
                ctx[(size_t)(b * S_ + q0 + rr) * D_ + hh * HD_ + wave * 16 + lr] = f2bf(o);
            }
        __syncthreads();   // protect Qs/Ks/Vs/state before next half
    }
}

// =====================================================================
// prep_layer: ONE layer's weight transposes+converts + qkv bias concat
// + FUSED LN1 (blocks 3075..5122 = 2048 LN rows x->h). Per-layer (r12
// algebra: up-front conversion cost +162us; per-layer keeps weights
// cache-hot). 5123 blocks.
// =====================================================================
#define DD_ (D_*D_)
#define DF_ (D_*F_)
#define WL_ (3*DD_ + DD_ + DF_ + DF_)
__global__ __launch_bounds__(256)
void prep_layer(const float* __restrict__ Wq, const float* __restrict__ Wk,
                const float* __restrict__ Wv, const float* __restrict__ Wo,
                const float* __restrict__ W1, const float* __restrict__ W2,
                const float* __restrict__ bq, const float* __restrict__ bk,
                const float* __restrict__ bv,
                ushort_t* __restrict__ wl, float* __restrict__ qkvb,
                const float* __restrict__ x, const float* __restrict__ ln_g,
                const float* __restrict__ ln_b, ushort_t* __restrict__ h)
{
    int bid = blockIdx.x;
    int tid = threadIdx.x;
    __shared__ float t[64][65];

    if (bid >= 3075) {
        // ---- fused LN1 row ----
        float* sb = &t[0][0];
        int row = bid - 3075;
        const float* xr = x + (size_t)row * D_;
        int c = tid * 4;
        f32x4 v = *(const f32x4*)&xr[c];
        float s = v[0] + v[1] + v[2] + v[3];
        s = blk_sum(s, sb);
        float mean = s * (1.0f / D_);
        f32x4 dv = v - mean;
        float sq = dv[0]*dv[0] + dv[1]*dv[1] + dv[2]*dv[2] + dv[3]*dv[3];
        sq = blk_sum(sq, sb);
        float rstd = rsqrtf(sq * (1.0f / D_) + EPSLN);
        u16x4 o;
        #pragma unroll
        for (int j = 0; j < 4; ++j)
            o[j] = f2bf(dv[j] * rstd * ln_g[c + j] + ln_b[c + j]);
        *(u16x4*)&h[(size_t)row * D_ + c] = o;
        return;
    }
    if (bid >= 3072) {
        int j = bid - 3072;
        const float* bsrc = (j == 0) ? bq : (j == 1) ? bk : bv;
        int c = tid * 4;
        *(f32x4*)&qkvb[j * 1024 + c] = *(const f32x4*)&bsrc[c];
        return;
    }
    int tx = tid & 63, ty = tid >> 6;
    const float* src; ushort_t* dst; int R, C, c0, r0;
    if (bid < 1024) {
        int mat = bid >> 8, tnum = bid & 255;
        src = (mat == 0) ? Wq : (mat == 1) ? Wk : (mat == 2) ? Wv : Wo;
        dst = (mat < 3) ? (wl + (size_t)mat * DD_) : (wl + 3 * (size_t)DD_);
        R = D_; C = D_;
        c0 = (tnum & 15) * 64; r0 = (tnum >> 4) * 64;
    } else if (bid < 2048) {
        int tnum = bid - 1024;
        src = W1; dst = wl + 4 * (size_t)DD_;
        R = D_; C = F_;
        c0 = (tnum & 63) * 64; r0 = (tnum >> 6) * 64;
    } else {
        int tnum = bid - 2048;
        src = W2; dst = wl + 4 * (size_t)DD_ + (size_t)DF_;
        R = F_; C = D_;
        c0 = (tnum & 15) * 64; r0 = (tnum >> 4) * 64;
    }
    #pragma unroll
    for (int i = 0; i < 16; ++i)
        t[ty + i * 4][tx] = src[(size_t)(r0 + ty + i * 4) * C + c0 + tx];
    __syncthreads();
    int u = tid & 31, v = tid >> 5;
    #pragma unroll
    for (int i = 0; i < 8; ++i) {
        int cc = v + i * 8;
        unsigned int val = (unsigned int)f2bf(t[u * 2][cc])
                         | ((unsigned int)f2bf(t[u * 2 + 1][cc]) << 16);
        *(unsigned int*)&dst[(size_t)(c0 + cc) * R + r0 + u * 2] = val;
    }
}

// ---- f32 [R,C] -> bf16 [C,R] transpose-convert, 64x64 tiles (Wout) ----
__global__ __launch_bounds__(256)
void tconv(const float* __restrict__ in, ushort_t* __restrict__ out, int R, int C)
{
    __shared__ float t[64][65];
    int c0 = blockIdx.x * 64, r0 = blockIdx.y * 64;
    int tid = threadIdx.x;
    int tx = tid & 63, ty = tid >> 6;
    #pragma unroll
    for (int i = 0; i < 16; ++i)
        t[ty + i * 4][tx] = in[(size_t)(r0 + ty + i * 4) * C + c0 + tx];
    __syncthreads();
    int u = tid & 31, v = tid >> 5;
    #pragma unroll
    for (int i = 0; i < 8; ++i) {
        int cc = v + i * 8;
        unsigned int val = (unsigned int)f2bf(t[u * 2][cc])
                         | ((unsigned int)f2bf(t[u * 2 + 1][cc]) << 16);
        *(unsigned int*)&out[(size_t)(c0 + cc) * R + r0 + u * 2] = val;
    }
}

// ---- embedding * sqrt(D) + sinusoidal PE -> x (f32) ----
__global__ __launch_bounds__(256)
void embed_pe(const int* __restrict__ ids, const float* __restrict__ emb,
              float* __restrict__ x)
{
    int row = blockIdx.x;
    int s   = row & (S_ - 1);
    int id  = ids[row];
    int d   = threadIdx.x * 4;
    f32x4 ev = *(const f32x4*)&emb[(size_t)id * D_ + d];
    f32x4 o;
    #pragma unroll
    for (int j = 0; j < 4; ++j) {
        int dd = d + j;
        int i  = dd >> 1;
        float div = expf(-(float)(2 * i) * (9.210340371976184f / 1024.0f));
        float arg = (float)s * div;
        float pe  = (dd & 1) ? cosf(arg) : sinf(arg);
        o[j] = ev[j] * 32.0f + pe;
    }
    *(f32x4*)&x[(size_t)row * D_ + d] = o;
}

// ---- LayerNorm row kernel: f32 in -> bf16 out ----
__global__ __launch_bounds__(256)
void ln_kernel(const float* __restrict__ x, const float* __restrict__ g,
               const float* __restrict__ b, ushort_t* __restrict__ out)
{
    __shared__ float sb[4];
    int row = blockIdx.x;
    const float* xr = x + (size_t)row * D_;
    int c = threadIdx.x * 4;
    f32x4 v = *(const f32x4*)&xr[c];
    float s = v[0] + v[1] + v[2] + v[3];
    s = blk_sum(s, sb);
    float mean = s * (1.0f / D_);
    f32x4 dv = v - mean;
    float sq = dv[0]*dv[0] + dv[1]*dv[1] + dv[2]*dv[2] + dv[3]*dv[3];
    sq = blk_sum(sq, sb);
    float rstd = rsqrtf(sq * (1.0f / D_) + EPSLN);
    u16x4 o;
    #pragma unroll
    for (int j = 0; j < 4; ++j)
        o[j] = f2bf(dv[j] * rstd * g[c + j] + b[c + j]);
    *(u16x4*)&out[(size_t)row * D_ + c] = o;
}

__global__ void ws_marker(float* o) { o[threadIdx.x] = -777777.0f; }

// =====================================================================
extern "C" void kernel_launch(void* const* d_in, const int* in_sizes, int n_in,
                              void* d_out, int out_size, void* d_ws, size_t ws_size,
                              hipStream_t stream)
{
    (void)in_sizes; (void)n_in; (void)out_size;
    const int*   ids  = (const int*)d_in[0];
    const float* emb  = (const float*)d_in[1];
    const float* Wq   = (const float*)d_in[2];
    const float* bq   = (const float*)d_in[3];
    const float* Wk   = (const float*)d_in[4];
    const float* bk   = (const float*)d_in[5];
    const float* Wv   = (const float*)d_in[6];
    const float* bv   = (const float*)d_in[7];
    const float* Wo   = (const float*)d_in[8];
    const float* bo   = (const float*)d_in[9];
    const float* ln1g = (const float*)d_in[10];
    const float* ln1b = (const float*)d_in[11];
    const float* ln2g = (const float*)d_in[12];
    const float* ln2b = (const float*)d_in[13];
    const float* W1   = (const float*)d_in[14];
    const float* b1   = (const float*)d_in[15];
    const float* W2   = (const float*)d_in[16];
    const float* b2   = (const float*)d_in[17];
    const float* fng  = (const float*)d_in[18];
    const float* fnb  = (const float*)d_in[19];
    const float* Wout = (const float*)d_in[20];
    const float* bout = (const float*)d_in[21];
    float* out = (float*)d_out;

    // ---- workspace layout ----
    char* base = (char*)d_ws;
    size_t off = 0;
    float*    x    = (float*)(base + off);    off += (size_t)MTOK * D_ * 4;
    ushort_t* h    = (ushort_t*)(base + off); off += (size_t)MTOK * D_ * 2;
    ushort_t* qkv  = (ushort_t*)(base + off); off += (size_t)MTOK * 3 * D_ * 2;
    ushort_t* vt   = (ushort_t*)(base + off); off += (size_t)B_ * H_ * HD_ * S_ * 2;
    ushort_t* ctx  = (ushort_t*)(base + off); off += (size_t)MTOK * D_ * 2;
    ushort_t* ff   = (ushort_t*)(base + off); off += (size_t)MTOK * F_ * 2;
    float*    qkvb = (float*)(base + off);    off += 3072 * 4;
    ushort_t* wouT = (ushort_t*)(base + off); off += (size_t)V_ * D_ * 2;
    ushort_t* wl   = (ushort_t*)(base + off); off += (size_t)WL_ * 2;
    if (ws_size < off) { ws_marker<<<1, 64, 0, stream>>>(out); return; }

    ushort_t* wqkvT = wl;
    ushort_t* woT   = wl + 3 * (size_t)DD_;
    ushort_t* w1T   = wl + 4 * (size_t)DD_;
    ushort_t* w2T   = wl + 4 * (size_t)DD_ + (size_t)DF_;

    embed_pe<<<MTOK, 256, 0, stream>>>(ids, emb, x);

    for (int i = 0; i < L_; ++i) {
        // per-layer prep (cache-hot weights) + fused LN1 (blocks 3075+)
        prep_layer<<<3075 + MTOK, 256, 0, stream>>>(
            Wq + (size_t)i * DD_, Wk + (size_t)i * DD_,
            Wv + (size_t)i * DD_, Wo + (size_t)i * DD_,
            W1 + (size_t)i * DF_, W2 + (size_t)i * DF_,
            bq + i * D_, bk + i * D_, bv + i * D_, wl, qkvb,
            x, ln1g + i * D_, ln1b + i * D_, h);

        // qkv = h @ [Wq|Wk|Wv] + bias; V cols also scattered into vt
        gemm_bt<64,false,false,true,true><<<dim3(16, 48), 256, 0, stream>>>(
            h, D_, wqkvT, D_, qkv, 3 * D_, qkvb, nullptr, MTOK, 3 * D_, D_, vt);

        flash_attn<<<dim3(8, B_ * H_), 256, 0, stream>>>(qkv, vt, ctx);

        // x = x + ctx @ Wo + bo
        gemm_bt<64,false,true,false,false><<<dim3(16, 16), 256, 0, stream>>>(
            ctx, D_, woT, D_, x, D_, bo + i * D_, x, MTOK, D_, D_, nullptr);

        ln_kernel<<<MTOK, 256, 0, stream>>>(x, ln2g + i * D_, ln2b + i * D_, h);

        // ff = gelu(h @ W1 + b1)
        gemm_bt<128,true,false,true,false><<<dim3(16, 32), 256, 0, stream>>>(
            h, D_, w1T, D_, ff, F_, b1 + i * F_, nullptr, MTOK, F_, D_, nullptr);

        // x = x + ff @ W2 + b2
        gemm_bt<64,false,true,false,false><<<dim3(16, 16), 256, 0, stream>>>(
            ff, F_, w2T, F_, x, D_, b2 + i * D_, x, MTOK, D_, F_, nullptr);
    }

    ln_kernel<<<MTOK, 256, 0, stream>>>(x, fng, fnb, h);
    tconv<<<dim3(500, 16), 256, 0, stream>>>(Wout, wouT, D_, V_);
    // logits: 256^2 tiles (measured-best for N=32000)
    gemm256<false,false><<<dim3(8, 125), 512, 0, stream>>>(
        h, D_, wouT, D_, out, V_, bout, MTOK, V_, D_);
}